// Round 2
// baseline (1306.492 us; speedup 1.0000x reference)
//
#include <hip/hip_runtime.h>

#define NN 50000
#define NE 1600000
#define DD 128
#define NH 9
#define NC 8
#define HCH 72
#define NEG 0.2f
#define NCHUNK 49   // ceil(50000/1024)

struct GP {
  const float* x; const int* ei; const float* W;
  const float* as; const float* ad; const float* b;
  float* h; float* a_s; float* a_d; float* out;
  int* hist; int* offs; int* chunks; int* csr;
};
struct GT { GP g[3]; };

// h = x@W (per (node,head): 8 channels), a_s/a_d dots, zero hist
__global__ __launch_bounds__(256) void k_gemm(GT t) {
  const GP G = t.g[blockIdx.z];
  const int gid = blockIdx.x * 256 + threadIdx.x;
  if (gid < NN) G.hist[gid] = 0;
  if (gid >= NN * NH) return;
  const int n = gid / NH;
  const int head = gid - n * NH;
  const float4* x4 = (const float4*)(G.x + (size_t)n * DD);
  const float* Wp = G.W + head * NC;
  float4 a0 = make_float4(0.f, 0.f, 0.f, 0.f);
  float4 a1 = make_float4(0.f, 0.f, 0.f, 0.f);
  auto step = [&](float xs, const float* wp) {
    float4 wa = *(const float4*)wp;
    float4 wb = *(const float4*)(wp + 4);
    a0.x = fmaf(xs, wa.x, a0.x); a0.y = fmaf(xs, wa.y, a0.y);
    a0.z = fmaf(xs, wa.z, a0.z); a0.w = fmaf(xs, wa.w, a0.w);
    a1.x = fmaf(xs, wb.x, a1.x); a1.y = fmaf(xs, wb.y, a1.y);
    a1.z = fmaf(xs, wb.z, a1.z); a1.w = fmaf(xs, wb.w, a1.w);
  };
  #pragma unroll 4
  for (int k4 = 0; k4 < DD / 4; ++k4) {
    const float4 xv = x4[k4];
    const float* wr = Wp + k4 * 4 * HCH;
    step(xv.x, wr);
    step(xv.y, wr + HCH);
    step(xv.z, wr + 2 * HCH);
    step(xv.w, wr + 3 * HCH);
  }
  const float* As = G.as + head * NC;
  const float* Ad = G.ad + head * NC;
  float ssrc = a0.x*As[0] + a0.y*As[1] + a0.z*As[2] + a0.w*As[3]
             + a1.x*As[4] + a1.y*As[5] + a1.z*As[6] + a1.w*As[7];
  float sdst = a0.x*Ad[0] + a0.y*Ad[1] + a0.z*Ad[2] + a0.w*Ad[3]
             + a1.x*Ad[4] + a1.y*Ad[5] + a1.z*Ad[6] + a1.w*Ad[7];
  G.a_s[n * NH + head] = ssrc;
  G.a_d[n * NH + head] = sdst;
  float4* h4 = (float4*)(G.h + (size_t)n * HCH + head * NC);
  h4[0] = a0; h4[1] = a1;
}

__global__ __launch_bounds__(256) void k_hist(GT t) {
  const GP G = t.g[blockIdx.z];
  const int e = blockIdx.x * 256 + threadIdx.x;
  if (e < NE) {
    int dst = G.ei[NE + e];
    atomicAdd(&G.hist[dst], 1);
  }
}

// per-chunk exclusive scan (1024-wide Hillis-Steele)
__global__ __launch_bounds__(1024) void k_scan1(GT t) {
  const GP G = t.g[blockIdx.z];
  __shared__ int s[1024];
  const int tid = threadIdx.x;
  const int i = blockIdx.x * 1024 + tid;
  int v = (i < NN) ? G.hist[i] : 0;
  s[tid] = v;
  __syncthreads();
  for (int off = 1; off < 1024; off <<= 1) {
    int u = (tid >= off) ? s[tid - off] : 0;
    __syncthreads();
    s[tid] += u;
    __syncthreads();
  }
  if (i < NN) G.offs[i] = s[tid] - v;          // exclusive within chunk
  if (tid == 1023) G.chunks[blockIdx.x] = s[1023];
}

// add chunk bases
__global__ __launch_bounds__(1024) void k_scan2(GT t) {
  const GP G = t.g[blockIdx.z];
  __shared__ int base[NCHUNK];
  if (threadIdx.x == 0) {
    int run = 0;
    for (int b = 0; b < NCHUNK; ++b) { base[b] = run; run += G.chunks[b]; }
  }
  __syncthreads();
  for (int i = threadIdx.x; i < NN; i += 1024) G.offs[i] += base[i >> 10];
}

// scatter src ids into CSR bins; offs becomes INCLUSIVE scan afterwards
__global__ __launch_bounds__(256) void k_scatter(GT t) {
  const GP G = t.g[blockIdx.z];
  const int e = blockIdx.x * 256 + threadIdx.x;
  if (e < NE) {
    int src = G.ei[e];
    int dst = G.ei[NE + e];
    int pos = atomicAdd(&G.offs[dst], 1);
    G.csr[pos] = src;
  }
}

// gather-style aggregation: thread (dst,head) walks its incoming edges.
// softmax shift-invariance: no segment_max needed; normalize at the end.
// self-loop contribution folded in analytically.
__global__ __launch_bounds__(256) void k_agg(GT t) {
  const GP G = t.g[blockIdx.z];
  const int gid = blockIdx.x * 256 + threadIdx.x;
  if (gid >= NN * NH) return;
  const int n = gid / NH;
  const int head = gid - n * NH;
  const int end = G.offs[n];
  const int start = (n == 0) ? 0 : G.offs[n - 1];
  const float ad_n = G.a_d[n * NH + head];
  const float as_n = G.a_s[n * NH + head];
  const float4* h4 = (const float4*)G.h;
  float sl = as_n + ad_n;
  sl = (sl > 0.f) ? sl : NEG * sl;
  float wl = __expf(sl);
  float4 ha = h4[n * (HCH / 4) + head * 2];
  float4 hb = h4[n * (HCH / 4) + head * 2 + 1];
  float denom = wl;
  float4 acc0, acc1;
  acc0.x = wl * ha.x; acc0.y = wl * ha.y; acc0.z = wl * ha.z; acc0.w = wl * ha.w;
  acc1.x = wl * hb.x; acc1.y = wl * hb.y; acc1.z = wl * hb.z; acc1.w = wl * hb.w;
  for (int e = start; e < end; ++e) {
    int src = G.csr[e];
    float s = G.a_s[src * NH + head] + ad_n;
    s = (s > 0.f) ? s : NEG * s;
    float w = __expf(s);
    float4 p = h4[src * (HCH / 4) + head * 2];
    float4 q = h4[src * (HCH / 4) + head * 2 + 1];
    denom += w;
    acc0.x = fmaf(w, p.x, acc0.x); acc0.y = fmaf(w, p.y, acc0.y);
    acc0.z = fmaf(w, p.z, acc0.z); acc0.w = fmaf(w, p.w, acc0.w);
    acc1.x = fmaf(w, q.x, acc1.x); acc1.y = fmaf(w, q.y, acc1.y);
    acc1.z = fmaf(w, q.z, acc1.z); acc1.w = fmaf(w, q.w, acc1.w);
  }
  float inv = 1.f / (denom + 1e-16f);
  const float* bp = G.b + head * NC;
  float4 o0, o1;
  o0.x = acc0.x * inv + bp[0]; o0.y = acc0.y * inv + bp[1];
  o0.z = acc0.z * inv + bp[2]; o0.w = acc0.w * inv + bp[3];
  o1.x = acc1.x * inv + bp[4]; o1.y = acc1.y * inv + bp[5];
  o1.z = acc1.z * inv + bp[6]; o1.w = acc1.w * inv + bp[7];
  float4* op = (float4*)(G.out + (size_t)n * HCH + head * NC);
  op[0] = o0; op[1] = o1;
}

// relu(concat) @ fnn_W + fnn_b -> softmax(2). One wave per node.
__global__ __launch_bounds__(256) void k_fnn(const float* __restrict__ o1,
                                             const float* __restrict__ o2,
                                             const float* __restrict__ o3,
                                             const float* __restrict__ fw,
                                             const float* __restrict__ fb,
                                             float* __restrict__ out) {
  const int tid = blockIdx.x * 256 + threadIdx.x;
  const int n = tid >> 6;
  const int lane = tid & 63;
  if (n >= NN) return;
  float acc0 = 0.f, acc1 = 0.f;
  for (int j = lane; j < 3 * HCH; j += 64) {
    const int g = j / HCH;
    const int c = j - g * HCH;
    const float* og = (g == 0) ? o1 : (g == 1) ? o2 : o3;
    float v = og[(size_t)n * HCH + c];
    v = v > 0.f ? v : 0.f;
    acc0 = fmaf(v, fw[2 * j], acc0);
    acc1 = fmaf(v, fw[2 * j + 1], acc1);
  }
  #pragma unroll
  for (int off = 32; off > 0; off >>= 1) {
    acc0 += __shfl_down(acc0, off, 64);
    acc1 += __shfl_down(acc1, off, 64);
  }
  if (lane == 0) {
    float l0 = acc0 + fb[0], l1 = acc1 + fb[1];
    float m = fmaxf(l0, l1);
    float e0 = __expf(l0 - m), e1 = __expf(l1 - m);
    float inv = 1.f / (e0 + e1);
    out[(size_t)n * 2] = e0 * inv;
    out[(size_t)n * 2 + 1] = e1 * inv;
  }
}

extern "C" void kernel_launch(void* const* d_in, const int* in_sizes, int n_in,
                              void* d_out, int out_size, void* d_ws, size_t ws_size,
                              hipStream_t stream) {
  (void)in_sizes; (void)n_in; (void)out_size; (void)ws_size;
  GT t;
  char* w = (char*)d_ws;
  size_t off = 0;
  auto carve = [&](size_t bytes) -> void* {
    void* p = w + off;
    off = (off + bytes + 255) & ~(size_t)255;
    return p;
  };
  for (int g = 0; g < 3; ++g) {
    GP& G = t.g[g];
    G.x  = (const float*)d_in[6 * g + 0];
    G.ei = (const int*)d_in[6 * g + 1];     // harness stores int64 inputs as int32
    G.W  = (const float*)d_in[6 * g + 2];
    G.as = (const float*)d_in[6 * g + 3];
    G.ad = (const float*)d_in[6 * g + 4];
    G.b  = (const float*)d_in[6 * g + 5];
    G.h    = (float*)carve((size_t)NN * HCH * 4);
    G.a_s  = (float*)carve((size_t)NN * NH * 4);
    G.a_d  = (float*)carve((size_t)NN * NH * 4);
    G.out  = (float*)carve((size_t)NN * HCH * 4);
    G.hist = (int*)carve((size_t)NN * 4);
    G.offs = (int*)carve((size_t)NN * 4);
    G.chunks = (int*)carve(256);
    G.csr  = (int*)carve((size_t)NE * 4);
  }
  const float* fw = (const float*)d_in[18];
  const float* fb = (const float*)d_in[19];
  float* outp = (float*)d_out;

  dim3 b256(256, 1, 1);
  k_gemm   <<<dim3((NN * NH + 255) / 256, 1, 3), b256, 0, stream>>>(t);
  k_hist   <<<dim3((NE + 255) / 256, 1, 3), b256, 0, stream>>>(t);
  k_scan1  <<<dim3(NCHUNK, 1, 3), dim3(1024, 1, 1), 0, stream>>>(t);
  k_scan2  <<<dim3(1, 1, 3), dim3(1024, 1, 1), 0, stream>>>(t);
  k_scatter<<<dim3((NE + 255) / 256, 1, 3), b256, 0, stream>>>(t);
  k_agg    <<<dim3((NN * NH + 255) / 256, 1, 3), b256, 0, stream>>>(t);
  k_fnn    <<<(NN * 64 + 255) / 256, b256, 0, stream>>>(t.g[0].out, t.g[1].out, t.g[2].out, fw, fb, outp);
}

// Round 3
// 1015.644 us; speedup vs baseline: 1.2864x; 1.2864x over previous
//
#include <hip/hip_runtime.h>

#define NN 50000
#define NE 1600000
#define DD 128
#define NH 9
#define NC 8
#define HCH 72
#define NEG 0.2f
#define NCHUNK 49      // ceil(50000/1024)
#define NBUCK 196      // ceil(50000/256), 256 dst nodes per bucket
#define EPB 8          // edges per thread in k_bin
#define BCH (256*EPB)  // 2048 edges per k_bin block

struct GP {
  const float* x; const int* ei; const float* W;
  const float* as; const float* ad; const float* b;
  float* h; float* a_s; float* a_d; float* out;
  int* hist; int* offs; int* chunks; int* bcursor;
  unsigned int* pairs; int* csr;
};
struct GT { GP g[3]; };

// h = x@W (per (node,head): 8 channels), a_s/a_d dots, zero hist
__global__ __launch_bounds__(256) void k_gemm(GT t) {
  const GP G = t.g[blockIdx.z];
  const int gid = blockIdx.x * 256 + threadIdx.x;
  if (gid < NN) G.hist[gid] = 0;
  if (gid >= NN * NH) return;
  const int n = gid / NH;
  const int head = gid - n * NH;
  const float4* x4 = (const float4*)(G.x + (size_t)n * DD);
  const float* Wp = G.W + head * NC;
  float4 a0 = make_float4(0.f, 0.f, 0.f, 0.f);
  float4 a1 = make_float4(0.f, 0.f, 0.f, 0.f);
  auto step = [&](float xs, const float* wp) {
    float4 wa = *(const float4*)wp;
    float4 wb = *(const float4*)(wp + 4);
    a0.x = fmaf(xs, wa.x, a0.x); a0.y = fmaf(xs, wa.y, a0.y);
    a0.z = fmaf(xs, wa.z, a0.z); a0.w = fmaf(xs, wa.w, a0.w);
    a1.x = fmaf(xs, wb.x, a1.x); a1.y = fmaf(xs, wb.y, a1.y);
    a1.z = fmaf(xs, wb.z, a1.z); a1.w = fmaf(xs, wb.w, a1.w);
  };
  #pragma unroll 4
  for (int k4 = 0; k4 < DD / 4; ++k4) {
    const float4 xv = x4[k4];
    const float* wr = Wp + k4 * 4 * HCH;
    step(xv.x, wr);
    step(xv.y, wr + HCH);
    step(xv.z, wr + 2 * HCH);
    step(xv.w, wr + 3 * HCH);
  }
  const float* As = G.as + head * NC;
  const float* Ad = G.ad + head * NC;
  float ssrc = a0.x*As[0] + a0.y*As[1] + a0.z*As[2] + a0.w*As[3]
             + a1.x*As[4] + a1.y*As[5] + a1.z*As[6] + a1.w*As[7];
  float sdst = a0.x*Ad[0] + a0.y*Ad[1] + a0.z*Ad[2] + a0.w*Ad[3]
             + a1.x*Ad[4] + a1.y*Ad[5] + a1.z*Ad[6] + a1.w*Ad[7];
  G.a_s[n * NH + head] = ssrc;
  G.a_d[n * NH + head] = sdst;
  float4* h4 = (float4*)(G.h + (size_t)n * HCH + head * NC);
  h4[0] = a0; h4[1] = a1;
}

__global__ __launch_bounds__(256) void k_hist(GT t) {
  const GP G = t.g[blockIdx.z];
  const int e = blockIdx.x * 256 + threadIdx.x;
  if (e < NE) {
    int dst = G.ei[NE + e];
    atomicAdd(&G.hist[dst], 1);
  }
}

// per-chunk exclusive scan (1024-wide Hillis-Steele)
__global__ __launch_bounds__(1024) void k_scan1(GT t) {
  const GP G = t.g[blockIdx.z];
  __shared__ int s[1024];
  const int tid = threadIdx.x;
  const int i = blockIdx.x * 1024 + tid;
  int v = (i < NN) ? G.hist[i] : 0;
  s[tid] = v;
  __syncthreads();
  for (int off = 1; off < 1024; off <<= 1) {
    int u = (tid >= off) ? s[tid - off] : 0;
    __syncthreads();
    s[tid] += u;
    __syncthreads();
  }
  if (i < NN) G.offs[i] = s[tid] - v;          // exclusive within chunk
  if (tid == 1023) G.chunks[blockIdx.x] = s[1023];
}

// add chunk bases; also emit per-bucket base cursors (exclusive scan @ b*256)
__global__ __launch_bounds__(1024) void k_scan2(GT t) {
  const GP G = t.g[blockIdx.z];
  __shared__ int base[NCHUNK];
  if (threadIdx.x == 0) {
    int run = 0;
    for (int b = 0; b < NCHUNK; ++b) { base[b] = run; run += G.chunks[b]; }
  }
  __syncthreads();
  for (int i = threadIdx.x; i < NN; i += 1024) {
    int v = G.offs[i] + base[i >> 10];
    G.offs[i] = v;
    if ((i & 255) == 0) G.bcursor[i >> 8] = v;
  }
}

// phase 1: bin edges into 196 dense per-bucket runs of packed (dst_local<<16|src)
__global__ __launch_bounds__(256) void k_bin(GT t) {
  const GP G = t.g[blockIdx.z];
  __shared__ int lh[NBUCK];    // per-block bucket histogram
  __shared__ int lbase[NBUCK]; // reserved global base per bucket
  __shared__ int lcur[NBUCK];  // local cursor
  const int tid = threadIdx.x;
  const int e0 = blockIdx.x * BCH;
  for (int i = tid; i < NBUCK; i += 256) lh[i] = 0;
  __syncthreads();
  int dsts[EPB], srcs[EPB];
  #pragma unroll
  for (int k = 0; k < EPB; ++k) {
    const int e = e0 + k * 256 + tid;
    if (e < NE) {
      int dst = G.ei[NE + e];
      srcs[k] = G.ei[e];
      dsts[k] = dst;
      atomicAdd(&lh[dst >> 8], 1);
    } else dsts[k] = -1;
  }
  __syncthreads();
  for (int i = tid; i < NBUCK; i += 256) {
    int c = lh[i];
    lbase[i] = c ? atomicAdd(&G.bcursor[i], c) : 0;
    lcur[i] = 0;
  }
  __syncthreads();
  #pragma unroll
  for (int k = 0; k < EPB; ++k) {
    if (dsts[k] >= 0) {
      int b = dsts[k] >> 8;
      int pos = lbase[b] + atomicAdd(&lcur[b], 1);
      G.pairs[pos] = (unsigned int)srcs[k] | ((unsigned int)(dsts[k] & 255) << 16);
    }
  }
}

// phase 2: one block per bucket; scatter src into the bucket's csr window
// (window ~32KB -> stays in one XCD's L2, lines written back once)
__global__ __launch_bounds__(256) void k_scat2(GT t) {
  const GP G = t.g[blockIdx.z];
  const int b = blockIdx.x;
  const int d0 = b << 8;
  const int d1 = min(d0 + 256, NN);
  __shared__ int cur[256];
  const int tid = threadIdx.x;
  if (d0 + tid < d1) cur[tid] = G.offs[d0 + tid];
  const int estart = G.offs[d0];
  const int eend = (d1 < NN) ? G.offs[d1] : NE;
  __syncthreads();
  for (int e = estart + tid; e < eend; e += 256) {
    unsigned int p = G.pairs[e];
    int src = (int)(p & 0xFFFFu);
    int dl = (int)(p >> 16);
    int pos = atomicAdd(&cur[dl], 1);
    G.csr[pos] = src;
  }
}

// gather-style aggregation: thread (dst,head) walks its incoming edges.
// softmax shift-invariance: no segment_max needed; normalize at the end.
// self-loop contribution folded in analytically.
__global__ __launch_bounds__(256) void k_agg(GT t) {
  const GP G = t.g[blockIdx.z];
  const int gid = blockIdx.x * 256 + threadIdx.x;
  if (gid >= NN * NH) return;
  const int n = gid / NH;
  const int head = gid - n * NH;
  const int start = G.offs[n];
  const int end = (n + 1 < NN) ? G.offs[n + 1] : NE;
  const float ad_n = G.a_d[n * NH + head];
  const float as_n = G.a_s[n * NH + head];
  const float4* h4 = (const float4*)G.h;
  float sl = as_n + ad_n;
  sl = (sl > 0.f) ? sl : NEG * sl;
  float wl = __expf(sl);
  float4 ha = h4[n * (HCH / 4) + head * 2];
  float4 hb = h4[n * (HCH / 4) + head * 2 + 1];
  float denom = wl;
  float4 acc0, acc1;
  acc0.x = wl * ha.x; acc0.y = wl * ha.y; acc0.z = wl * ha.z; acc0.w = wl * ha.w;
  acc1.x = wl * hb.x; acc1.y = wl * hb.y; acc1.z = wl * hb.z; acc1.w = wl * hb.w;
  for (int e = start; e < end; ++e) {
    int src = G.csr[e];
    float s = G.a_s[src * NH + head] + ad_n;
    s = (s > 0.f) ? s : NEG * s;
    float w = __expf(s);
    float4 p = h4[src * (HCH / 4) + head * 2];
    float4 q = h4[src * (HCH / 4) + head * 2 + 1];
    denom += w;
    acc0.x = fmaf(w, p.x, acc0.x); acc0.y = fmaf(w, p.y, acc0.y);
    acc0.z = fmaf(w, p.z, acc0.z); acc0.w = fmaf(w, p.w, acc0.w);
    acc1.x = fmaf(w, q.x, acc1.x); acc1.y = fmaf(w, q.y, acc1.y);
    acc1.z = fmaf(w, q.z, acc1.z); acc1.w = fmaf(w, q.w, acc1.w);
  }
  float inv = 1.f / (denom + 1e-16f);
  const float* bp = G.b + head * NC;
  float4 o0, o1;
  o0.x = acc0.x * inv + bp[0]; o0.y = acc0.y * inv + bp[1];
  o0.z = acc0.z * inv + bp[2]; o0.w = acc0.w * inv + bp[3];
  o1.x = acc1.x * inv + bp[4]; o1.y = acc1.y * inv + bp[5];
  o1.z = acc1.z * inv + bp[6]; o1.w = acc1.w * inv + bp[7];
  float4* op = (float4*)(G.out + (size_t)n * HCH + head * NC);
  op[0] = o0; op[1] = o1;
}

// relu(concat) @ fnn_W + fnn_b -> softmax(2). One wave per node.
__global__ __launch_bounds__(256) void k_fnn(const float* __restrict__ o1,
                                             const float* __restrict__ o2,
                                             const float* __restrict__ o3,
                                             const float* __restrict__ fw,
                                             const float* __restrict__ fb,
                                             float* __restrict__ out) {
  const int tid = blockIdx.x * 256 + threadIdx.x;
  const int n = tid >> 6;
  const int lane = tid & 63;
  if (n >= NN) return;
  float acc0 = 0.f, acc1 = 0.f;
  for (int j = lane; j < 3 * HCH; j += 64) {
    const int g = j / HCH;
    const int c = j - g * HCH;
    const float* og = (g == 0) ? o1 : (g == 1) ? o2 : o3;
    float v = og[(size_t)n * HCH + c];
    v = v > 0.f ? v : 0.f;
    acc0 = fmaf(v, fw[2 * j], acc0);
    acc1 = fmaf(v, fw[2 * j + 1], acc1);
  }
  #pragma unroll
  for (int off = 32; off > 0; off >>= 1) {
    acc0 += __shfl_down(acc0, off, 64);
    acc1 += __shfl_down(acc1, off, 64);
  }
  if (lane == 0) {
    float l0 = acc0 + fb[0], l1 = acc1 + fb[1];
    float m = fmaxf(l0, l1);
    float e0 = __expf(l0 - m), e1 = __expf(l1 - m);
    float inv = 1.f / (e0 + e1);
    out[(size_t)n * 2] = e0 * inv;
    out[(size_t)n * 2 + 1] = e1 * inv;
  }
}

extern "C" void kernel_launch(void* const* d_in, const int* in_sizes, int n_in,
                              void* d_out, int out_size, void* d_ws, size_t ws_size,
                              hipStream_t stream) {
  (void)in_sizes; (void)n_in; (void)out_size; (void)ws_size;
  GT t;
  char* w = (char*)d_ws;
  size_t off = 0;
  auto carve = [&](size_t bytes) -> void* {
    void* p = w + off;
    off = (off + bytes + 255) & ~(size_t)255;
    return p;
  };
  for (int g = 0; g < 3; ++g) {
    GP& G = t.g[g];
    G.x  = (const float*)d_in[6 * g + 0];
    G.ei = (const int*)d_in[6 * g + 1];     // harness stores int64 inputs as int32
    G.W  = (const float*)d_in[6 * g + 2];
    G.as = (const float*)d_in[6 * g + 3];
    G.ad = (const float*)d_in[6 * g + 4];
    G.b  = (const float*)d_in[6 * g + 5];
    G.h    = (float*)carve((size_t)NN * HCH * 4);
    G.a_s  = (float*)carve((size_t)NN * NH * 4);
    G.a_d  = (float*)carve((size_t)NN * NH * 4);
    G.out  = (float*)carve((size_t)NN * HCH * 4);
    G.hist = (int*)carve((size_t)NN * 4);
    G.offs = (int*)carve((size_t)NN * 4);
    G.chunks = (int*)carve(256);
    G.bcursor = (int*)carve((size_t)NBUCK * 4);
    G.pairs = (unsigned int*)carve((size_t)NE * 4);
    G.csr  = (int*)carve((size_t)NE * 4);
  }
  const float* fw = (const float*)d_in[18];
  const float* fb = (const float*)d_in[19];
  float* outp = (float*)d_out;

  dim3 b256(256, 1, 1);
  k_gemm   <<<dim3((NN * NH + 255) / 256, 1, 3), b256, 0, stream>>>(t);
  k_hist   <<<dim3((NE + 255) / 256, 1, 3), b256, 0, stream>>>(t);
  k_scan1  <<<dim3(NCHUNK, 1, 3), dim3(1024, 1, 1), 0, stream>>>(t);
  k_scan2  <<<dim3(1, 1, 3), dim3(1024, 1, 1), 0, stream>>>(t);
  k_bin    <<<dim3((NE + BCH - 1) / BCH, 1, 3), b256, 0, stream>>>(t);
  k_scat2  <<<dim3(NBUCK, 1, 3), b256, 0, stream>>>(t);
  k_agg    <<<dim3((NN * NH + 255) / 256, 1, 3), b256, 0, stream>>>(t);
  k_fnn    <<<(NN * 64 + 255) / 256, b256, 0, stream>>>(t.g[0].out, t.g[1].out, t.g[2].out, fw, fb, outp);
}

// Round 5
// 895.000 us; speedup vs baseline: 1.4598x; 1.1348x over previous
//
#include <hip/hip_runtime.h>
#include <hip/hip_fp16.h>

#define NN 50000
#define NE 1600000
#define DD 128
#define NH 9
#define NC 8
#define HCH 72
#define NEG 0.2f
#define NCHUNK 49      // ceil(50000/1024)
#define NBUCK 196      // ceil(50000/256), 256 dst nodes per bucket
#define EPB 8          // edges per thread in k_bin
#define BCH (256*EPB)  // 2048 edges per k_bin block

__device__ __forceinline__ unsigned short f2h(float f) {
  return __half_as_ushort(__float2half_rn(f));
}
__device__ __forceinline__ float h2f(unsigned short u) {
  return __half2float(__ushort_as_half(u));
}
__device__ __forceinline__ float hlo(unsigned u) {
  return __half2float(__ushort_as_half((unsigned short)(u & 0xFFFFu)));
}
__device__ __forceinline__ float hhi(unsigned u) {
  return __half2float(__ushort_as_half((unsigned short)(u >> 16)));
}

struct GP {
  const float* x; const int* ei; const float* W;
  const float* as; const float* ad; const float* b;
  uint4* h2;                // [NN*9] uint4: 8 fp16 channels per (node,head)
  unsigned short* as2;      // [NN*9] fp16 src-attention scores
  float* a_d; float* out;
  int* hist; int* offs; int* chunks; int* bcursor;
  unsigned int* pairs; int* csr;
};
struct GT { GP g[3]; };

// h = x@W (fp32 accum, fp16 store), a_s/a_d dots, zero hist
__global__ __launch_bounds__(256) void k_gemm(GT t) {
  const GP G = t.g[blockIdx.z];
  const int gid = blockIdx.x * 256 + threadIdx.x;
  if (gid < NN) G.hist[gid] = 0;
  if (gid >= NN * NH) return;
  const int n = gid / NH;
  const int head = gid - n * NH;
  const float4* x4 = (const float4*)(G.x + (size_t)n * DD);
  const float* Wp = G.W + head * NC;
  float4 a0 = make_float4(0.f, 0.f, 0.f, 0.f);
  float4 a1 = make_float4(0.f, 0.f, 0.f, 0.f);
  auto step = [&](float xs, const float* wp) {
    float4 wa = *(const float4*)wp;
    float4 wb = *(const float4*)(wp + 4);
    a0.x = fmaf(xs, wa.x, a0.x); a0.y = fmaf(xs, wa.y, a0.y);
    a0.z = fmaf(xs, wa.z, a0.z); a0.w = fmaf(xs, wa.w, a0.w);
    a1.x = fmaf(xs, wb.x, a1.x); a1.y = fmaf(xs, wb.y, a1.y);
    a1.z = fmaf(xs, wb.z, a1.z); a1.w = fmaf(xs, wb.w, a1.w);
  };
  #pragma unroll 4
  for (int k4 = 0; k4 < DD / 4; ++k4) {
    const float4 xv = x4[k4];
    const float* wr = Wp + k4 * 4 * HCH;
    step(xv.x, wr);
    step(xv.y, wr + HCH);
    step(xv.z, wr + 2 * HCH);
    step(xv.w, wr + 3 * HCH);
  }
  const float* As = G.as + head * NC;
  const float* Ad = G.ad + head * NC;
  float ssrc = a0.x*As[0] + a0.y*As[1] + a0.z*As[2] + a0.w*As[3]
             + a1.x*As[4] + a1.y*As[5] + a1.z*As[6] + a1.w*As[7];
  float sdst = a0.x*Ad[0] + a0.y*Ad[1] + a0.z*Ad[2] + a0.w*Ad[3]
             + a1.x*Ad[4] + a1.y*Ad[5] + a1.z*Ad[6] + a1.w*Ad[7];
  G.as2[n * NH + head] = f2h(ssrc);
  G.a_d[n * NH + head] = sdst;
  uint4 hv;
  hv.x = (unsigned)f2h(a0.x) | ((unsigned)f2h(a0.y) << 16);
  hv.y = (unsigned)f2h(a0.z) | ((unsigned)f2h(a0.w) << 16);
  hv.z = (unsigned)f2h(a1.x) | ((unsigned)f2h(a1.y) << 16);
  hv.w = (unsigned)f2h(a1.z) | ((unsigned)f2h(a1.w) << 16);
  G.h2[(size_t)n * NH + head] = hv;
}

__global__ __launch_bounds__(256) void k_hist(GT t) {
  const GP G = t.g[blockIdx.z];
  const int e = blockIdx.x * 256 + threadIdx.x;
  if (e < NE) {
    int dst = G.ei[NE + e];
    atomicAdd(&G.hist[dst], 1);
  }
}

// per-chunk exclusive scan (1024-wide Hillis-Steele)
__global__ __launch_bounds__(1024) void k_scan1(GT t) {
  const GP G = t.g[blockIdx.z];
  __shared__ int s[1024];
  const int tid = threadIdx.x;
  const int i = blockIdx.x * 1024 + tid;
  int v = (i < NN) ? G.hist[i] : 0;
  s[tid] = v;
  __syncthreads();
  for (int off = 1; off < 1024; off <<= 1) {
    int u = (tid >= off) ? s[tid - off] : 0;
    __syncthreads();
    s[tid] += u;
    __syncthreads();
  }
  if (i < NN) G.offs[i] = s[tid] - v;          // exclusive within chunk
  if (tid == 1023) G.chunks[blockIdx.x] = s[1023];
}

// add chunk bases; also emit per-bucket base cursors (exclusive scan @ b*256)
__global__ __launch_bounds__(1024) void k_scan2(GT t) {
  const GP G = t.g[blockIdx.z];
  __shared__ int base[NCHUNK];
  if (threadIdx.x == 0) {
    int run = 0;
    for (int b = 0; b < NCHUNK; ++b) { base[b] = run; run += G.chunks[b]; }
  }
  __syncthreads();
  for (int i = threadIdx.x; i < NN; i += 1024) {
    int v = G.offs[i] + base[i >> 10];
    G.offs[i] = v;
    if ((i & 255) == 0) G.bcursor[i >> 8] = v;
  }
}

// phase 1: bin edges into 196 dense per-bucket runs of packed (dst_local<<16|src)
__global__ __launch_bounds__(256) void k_bin(GT t) {
  const GP G = t.g[blockIdx.z];
  __shared__ int lh[NBUCK];    // per-block bucket histogram
  __shared__ int lbase[NBUCK]; // reserved global base per bucket
  __shared__ int lcur[NBUCK];  // local cursor
  const int tid = threadIdx.x;
  const int e0 = blockIdx.x * BCH;
  for (int i = tid; i < NBUCK; i += 256) lh[i] = 0;
  __syncthreads();
  int dsts[EPB], srcs[EPB];
  #pragma unroll
  for (int k = 0; k < EPB; ++k) {
    const int e = e0 + k * 256 + tid;
    if (e < NE) {
      int dst = G.ei[NE + e];
      srcs[k] = G.ei[e];
      dsts[k] = dst;
      atomicAdd(&lh[dst >> 8], 1);
    } else dsts[k] = -1;
  }
  __syncthreads();
  for (int i = tid; i < NBUCK; i += 256) {
    int c = lh[i];
    lbase[i] = c ? atomicAdd(&G.bcursor[i], c) : 0;
    lcur[i] = 0;
  }
  __syncthreads();
  #pragma unroll
  for (int k = 0; k < EPB; ++k) {
    if (dsts[k] >= 0) {
      int b = dsts[k] >> 8;
      int pos = lbase[b] + atomicAdd(&lcur[b], 1);
      G.pairs[pos] = (unsigned int)srcs[k] | ((unsigned int)(dsts[k] & 255) << 16);
    }
  }
}

// phase 2: one block per bucket; scatter src into the bucket's csr window
__global__ __launch_bounds__(256) void k_scat2(GT t) {
  const GP G = t.g[blockIdx.z];
  const int b = blockIdx.x;
  const int d0 = b << 8;
  const int d1 = min(d0 + 256, NN);
  __shared__ int cur[256];
  const int tid = threadIdx.x;
  if (d0 + tid < d1) cur[tid] = G.offs[d0 + tid];
  const int estart = G.offs[d0];
  const int eend = (d1 < NN) ? G.offs[d1] : NE;
  __syncthreads();
  for (int e = estart + tid; e < eend; e += 256) {
    unsigned int p = G.pairs[e];
    int src = (int)(p & 0xFFFFu);
    int dl = (int)(p >> 16);
    int pos = atomicAdd(&cur[dl], 1);
    G.csr[pos] = src;
  }
}

// gather aggregation over fp16 h2/as2: thread (dst,head) walks incoming edges.
__global__ __launch_bounds__(256) void k_agg(GT t) {
  const GP G = t.g[blockIdx.z];
  const int gid = blockIdx.x * 256 + threadIdx.x;
  if (gid >= NN * NH) return;
  const int n = gid / NH;
  const int head = gid - n * NH;
  const int start = G.offs[n];
  const int end = (n + 1 < NN) ? G.offs[n + 1] : NE;
  const float ad_n = G.a_d[n * NH + head];
  const float as_n = h2f(G.as2[n * NH + head]);
  float sl = as_n + ad_n;
  sl = (sl > 0.f) ? sl : NEG * sl;
  float wl = __expf(sl);
  uint4 hs = G.h2[(size_t)n * NH + head];
  float denom = wl;
  float4 acc0, acc1;
  acc0.x = wl * hlo(hs.x); acc0.y = wl * hhi(hs.x);
  acc0.z = wl * hlo(hs.y); acc0.w = wl * hhi(hs.y);
  acc1.x = wl * hlo(hs.z); acc1.y = wl * hhi(hs.z);
  acc1.z = wl * hlo(hs.w); acc1.w = wl * hhi(hs.w);
  for (int e = start; e < end; ++e) {
    int src = G.csr[e];
    float s = h2f(G.as2[src * NH + head]) + ad_n;
    s = (s > 0.f) ? s : NEG * s;
    float w = __expf(s);
    uint4 hv = G.h2[(size_t)src * NH + head];
    denom += w;
    acc0.x = fmaf(w, hlo(hv.x), acc0.x); acc0.y = fmaf(w, hhi(hv.x), acc0.y);
    acc0.z = fmaf(w, hlo(hv.y), acc0.z); acc0.w = fmaf(w, hhi(hv.y), acc0.w);
    acc1.x = fmaf(w, hlo(hv.z), acc1.x); acc1.y = fmaf(w, hhi(hv.z), acc1.y);
    acc1.z = fmaf(w, hlo(hv.w), acc1.z); acc1.w = fmaf(w, hhi(hv.w), acc1.w);
  }
  float inv = 1.f / (denom + 1e-16f);
  const float* bp = G.b + head * NC;
  float4 o0, o1;
  o0.x = acc0.x * inv + bp[0]; o0.y = acc0.y * inv + bp[1];
  o0.z = acc0.z * inv + bp[2]; o0.w = acc0.w * inv + bp[3];
  o1.x = acc1.x * inv + bp[4]; o1.y = acc1.y * inv + bp[5];
  o1.z = acc1.z * inv + bp[6]; o1.w = acc1.w * inv + bp[7];
  float4* op = (float4*)(G.out + (size_t)n * HCH + head * NC);
  op[0] = o0; op[1] = o1;
}

// relu(concat) @ fnn_W + fnn_b -> softmax(2). One wave per node.
__global__ __launch_bounds__(256) void k_fnn(const float* __restrict__ o1,
                                             const float* __restrict__ o2,
                                             const float* __restrict__ o3,
                                             const float* __restrict__ fw,
                                             const float* __restrict__ fb,
                                             float* __restrict__ out) {
  const int tid = blockIdx.x * 256 + threadIdx.x;
  const int n = tid >> 6;
  const int lane = tid & 63;
  if (n >= NN) return;
  float acc0 = 0.f, acc1 = 0.f;
  for (int j = lane; j < 3 * HCH; j += 64) {
    const int g = j / HCH;
    const int c = j - g * HCH;
    const float* og = (g == 0) ? o1 : (g == 1) ? o2 : o3;
    float v = og[(size_t)n * HCH + c];
    v = v > 0.f ? v : 0.f;
    acc0 = fmaf(v, fw[2 * j], acc0);
    acc1 = fmaf(v, fw[2 * j + 1], acc1);
  }
  #pragma unroll
  for (int off = 32; off > 0; off >>= 1) {
    acc0 += __shfl_down(acc0, off, 64);
    acc1 += __shfl_down(acc1, off, 64);
  }
  if (lane == 0) {
    float l0 = acc0 + fb[0], l1 = acc1 + fb[1];
    float m = fmaxf(l0, l1);
    float e0 = __expf(l0 - m), e1 = __expf(l1 - m);
    float inv = 1.f / (e0 + e1);
    out[(size_t)n * 2] = e0 * inv;
    out[(size_t)n * 2 + 1] = e1 * inv;
  }
}

extern "C" void kernel_launch(void* const* d_in, const int* in_sizes, int n_in,
                              void* d_out, int out_size, void* d_ws, size_t ws_size,
                              hipStream_t stream) {
  (void)in_sizes; (void)n_in; (void)out_size; (void)ws_size;
  GT t;
  char* w = (char*)d_ws;
  size_t off = 0;
  auto carve = [&](size_t bytes) -> void* {
    void* p = w + off;
    off = (off + bytes + 255) & ~(size_t)255;
    return p;
  };
  for (int g = 0; g < 3; ++g) {
    GP& G = t.g[g];
    G.x  = (const float*)d_in[6 * g + 0];
    G.ei = (const int*)d_in[6 * g + 1];     // harness stores int64 inputs as int32
    G.W  = (const float*)d_in[6 * g + 2];
    G.as = (const float*)d_in[6 * g + 3];
    G.ad = (const float*)d_in[6 * g + 4];
    G.b  = (const float*)d_in[6 * g + 5];
    G.h2   = (uint4*)carve((size_t)NN * NH * 16);
    G.as2  = (unsigned short*)carve((size_t)NN * NH * 2);
    G.a_d  = (float*)carve((size_t)NN * NH * 4);
    G.out  = (float*)carve((size_t)NN * HCH * 4);
    G.hist = (int*)carve((size_t)NN * 4);
    G.offs = (int*)carve((size_t)NN * 4);
    G.chunks = (int*)carve(256);
    G.bcursor = (int*)carve((size_t)NBUCK * 4);
    G.pairs = (unsigned int*)carve((size_t)NE * 4);
    G.csr  = (int*)carve((size_t)NE * 4);
  }
  const float* fw = (const float*)d_in[18];
  const float* fb = (const float*)d_in[19];
  float* outp = (float*)d_out;

  dim3 b256(256, 1, 1);
  k_gemm   <<<dim3((NN * NH + 255) / 256, 1, 3), b256, 0, stream>>>(t);
  k_hist   <<<dim3((NE + 255) / 256, 1, 3), b256, 0, stream>>>(t);
  k_scan1  <<<dim3(NCHUNK, 1, 3), dim3(1024, 1, 1), 0, stream>>>(t);
  k_scan2  <<<dim3(1, 1, 3), dim3(1024, 1, 1), 0, stream>>>(t);
  k_bin    <<<dim3((NE + BCH - 1) / BCH, 1, 3), b256, 0, stream>>>(t);
  k_scat2  <<<dim3(NBUCK, 1, 3), b256, 0, stream>>>(t);
  k_agg    <<<dim3((NN * NH + 255) / 256, 1, 3), b256, 0, stream>>>(t);
  k_fnn    <<<(NN * 64 + 255) / 256, b256, 0, stream>>>(t.g[0].out, t.g[1].out, t.g[2].out, fw, fb, outp);
}

// Round 6
// 739.294 us; speedup vs baseline: 1.7672x; 1.2106x over previous
//
#include <hip/hip_runtime.h>
#include <hip/hip_fp16.h>

#define NN 50000
#define NE 1600000
#define DD 128
#define NH 9
#define NC 8
#define HCH 72
#define NEG 0.2f
#define NCHUNK 49      // ceil(50000/1024)
#define NBUCK 196      // ceil(50000/256), 256 dst nodes per bucket
#define EPB 8          // edges per thread in k_bin
#define BCH (256*EPB)  // 2048 edges per k_bin block

__device__ __forceinline__ unsigned short f2h(float f) {
  return __half_as_ushort(__float2half_rn(f));
}
__device__ __forceinline__ float h2f(unsigned short u) {
  return __half2float(__ushort_as_half(u));
}
__device__ __forceinline__ float hlo(unsigned u) {
  return __half2float(__ushort_as_half((unsigned short)(u & 0xFFFFu)));
}
__device__ __forceinline__ float hhi(unsigned u) {
  return __half2float(__ushort_as_half((unsigned short)(u >> 16)));
}

struct GP {
  const float* x; const int* ei; const float* W;
  const float* as; const float* ad; const float* b;
  uint4* h2;                // [NN*9] uint4: 8 fp16 channels per (node,head)
  unsigned short* as2;      // [NN*9] fp16 src-attention scores
  float* a_d; float* out;
  int* hist; int* offs; int* chunks; int* bcursor;
  unsigned int* pairs; int* csr;
};
struct GT { GP g[3]; };

// h = x@W: one thread per NODE, all 72 channels in registers.
// W staged in LDS (wave-uniform broadcast reads); x read as 32 float4/thread.
__global__ __launch_bounds__(256) void k_gemm(GT t) {
  const GP G = t.g[blockIdx.z];
  __shared__ float Wl[DD * HCH];   // 36 KB
  const int tid = threadIdx.x;
  {
    const float4* Wg = (const float4*)G.W;
    float4* Wd = (float4*)Wl;
    #pragma unroll
    for (int i = 0; i < 9; ++i) Wd[tid + 256 * i] = Wg[tid + 256 * i];  // 2304 = 256*9
  }
  const int n = blockIdx.x * 256 + tid;
  if (n < NN) G.hist[n] = 0;
  __syncthreads();
  if (n >= NN) return;

  float4 acc[18];
  #pragma unroll
  for (int i = 0; i < 18; ++i) acc[i] = make_float4(0.f, 0.f, 0.f, 0.f);
  const float4* x4 = (const float4*)(G.x + (size_t)n * DD);

  for (int k4 = 0; k4 < DD / 4; ++k4) {
    const float4 xv = x4[k4];
    const float* w0 = &Wl[(k4 * 4) * HCH];
    #pragma unroll
    for (int kk = 0; kk < 4; ++kk) {
      const float xk = (kk == 0) ? xv.x : (kk == 1) ? xv.y : (kk == 2) ? xv.z : xv.w;
      const float4* wr = (const float4*)(w0 + kk * HCH);
      #pragma unroll
      for (int c4 = 0; c4 < 18; ++c4) {
        float4 wv = wr[c4];                       // wave-uniform LDS broadcast
        acc[c4].x = fmaf(xk, wv.x, acc[c4].x);
        acc[c4].y = fmaf(xk, wv.y, acc[c4].y);
        acc[c4].z = fmaf(xk, wv.z, acc[c4].z);
        acc[c4].w = fmaf(xk, wv.w, acc[c4].w);
      }
    }
  }

  // epilogue: per head, attention dots + fp16 pack
  #pragma unroll
  for (int hd = 0; hd < NH; ++hd) {
    const float4 a0 = acc[2 * hd];
    const float4 a1 = acc[2 * hd + 1];
    const float4 As0 = *(const float4*)(G.as + hd * NC);
    const float4 As1 = *(const float4*)(G.as + hd * NC + 4);
    const float4 Ad0 = *(const float4*)(G.ad + hd * NC);
    const float4 Ad1 = *(const float4*)(G.ad + hd * NC + 4);
    float ssrc = a0.x*As0.x + a0.y*As0.y + a0.z*As0.z + a0.w*As0.w
               + a1.x*As1.x + a1.y*As1.y + a1.z*As1.z + a1.w*As1.w;
    float sdst = a0.x*Ad0.x + a0.y*Ad0.y + a0.z*Ad0.z + a0.w*Ad0.w
               + a1.x*Ad1.x + a1.y*Ad1.y + a1.z*Ad1.z + a1.w*Ad1.w;
    G.as2[n * NH + hd] = f2h(ssrc);
    G.a_d[n * NH + hd] = sdst;
    uint4 hv;
    hv.x = (unsigned)f2h(a0.x) | ((unsigned)f2h(a0.y) << 16);
    hv.y = (unsigned)f2h(a0.z) | ((unsigned)f2h(a0.w) << 16);
    hv.z = (unsigned)f2h(a1.x) | ((unsigned)f2h(a1.y) << 16);
    hv.w = (unsigned)f2h(a1.z) | ((unsigned)f2h(a1.w) << 16);
    G.h2[(size_t)n * NH + hd] = hv;
  }
}

__global__ __launch_bounds__(256) void k_hist(GT t) {
  const GP G = t.g[blockIdx.z];
  const int e = blockIdx.x * 256 + threadIdx.x;
  if (e < NE) {
    int dst = G.ei[NE + e];
    atomicAdd(&G.hist[dst], 1);
  }
}

// per-chunk exclusive scan (1024-wide Hillis-Steele)
__global__ __launch_bounds__(1024) void k_scan1(GT t) {
  const GP G = t.g[blockIdx.z];
  __shared__ int s[1024];
  const int tid = threadIdx.x;
  const int i = blockIdx.x * 1024 + tid;
  int v = (i < NN) ? G.hist[i] : 0;
  s[tid] = v;
  __syncthreads();
  for (int off = 1; off < 1024; off <<= 1) {
    int u = (tid >= off) ? s[tid - off] : 0;
    __syncthreads();
    s[tid] += u;
    __syncthreads();
  }
  if (i < NN) G.offs[i] = s[tid] - v;          // exclusive within chunk
  if (tid == 1023) G.chunks[blockIdx.x] = s[1023];
}

// add chunk bases; also emit per-bucket base cursors (exclusive scan @ b*256)
__global__ __launch_bounds__(1024) void k_scan2(GT t) {
  const GP G = t.g[blockIdx.z];
  __shared__ int base[NCHUNK];
  if (threadIdx.x == 0) {
    int run = 0;
    for (int b = 0; b < NCHUNK; ++b) { base[b] = run; run += G.chunks[b]; }
  }
  __syncthreads();
  for (int i = threadIdx.x; i < NN; i += 1024) {
    int v = G.offs[i] + base[i >> 10];
    G.offs[i] = v;
    if ((i & 255) == 0) G.bcursor[i >> 8] = v;
  }
}

// phase 1: bin edges into 196 dense per-bucket runs of packed (dst_local<<16|src)
__global__ __launch_bounds__(256) void k_bin(GT t) {
  const GP G = t.g[blockIdx.z];
  __shared__ int lh[NBUCK];    // per-block bucket histogram
  __shared__ int lbase[NBUCK]; // reserved global base per bucket
  __shared__ int lcur[NBUCK];  // local cursor
  const int tid = threadIdx.x;
  const int e0 = blockIdx.x * BCH;
  for (int i = tid; i < NBUCK; i += 256) lh[i] = 0;
  __syncthreads();
  int dsts[EPB], srcs[EPB];
  #pragma unroll
  for (int k = 0; k < EPB; ++k) {
    const int e = e0 + k * 256 + tid;
    if (e < NE) {
      int dst = G.ei[NE + e];
      srcs[k] = G.ei[e];
      dsts[k] = dst;
      atomicAdd(&lh[dst >> 8], 1);
    } else dsts[k] = -1;
  }
  __syncthreads();
  for (int i = tid; i < NBUCK; i += 256) {
    int c = lh[i];
    lbase[i] = c ? atomicAdd(&G.bcursor[i], c) : 0;
    lcur[i] = 0;
  }
  __syncthreads();
  #pragma unroll
  for (int k = 0; k < EPB; ++k) {
    if (dsts[k] >= 0) {
      int b = dsts[k] >> 8;
      int pos = lbase[b] + atomicAdd(&lcur[b], 1);
      G.pairs[pos] = (unsigned int)srcs[k] | ((unsigned int)(dsts[k] & 255) << 16);
    }
  }
}

// phase 2: one block per bucket; scatter src into the bucket's csr window
__global__ __launch_bounds__(256) void k_scat2(GT t) {
  const GP G = t.g[blockIdx.z];
  const int b = blockIdx.x;
  const int d0 = b << 8;
  const int d1 = min(d0 + 256, NN);
  __shared__ int cur[256];
  const int tid = threadIdx.x;
  if (d0 + tid < d1) cur[tid] = G.offs[d0 + tid];
  const int estart = G.offs[d0];
  const int eend = (d1 < NN) ? G.offs[d1] : NE;
  __syncthreads();
  for (int e = estart + tid; e < eend; e += 256) {
    unsigned int p = G.pairs[e];
    int src = (int)(p & 0xFFFFu);
    int dl = (int)(p >> 16);
    int pos = atomicAdd(&cur[dl], 1);
    G.csr[pos] = src;
  }
}

// gather aggregation over fp16 h2/as2: thread (dst,head) walks incoming edges.
__global__ __launch_bounds__(256) void k_agg(GT t) {
  const GP G = t.g[blockIdx.z];
  const int gid = blockIdx.x * 256 + threadIdx.x;
  if (gid >= NN * NH) return;
  const int n = gid / NH;
  const int head = gid - n * NH;
  const int start = G.offs[n];
  const int end = (n + 1 < NN) ? G.offs[n + 1] : NE;
  const float ad_n = G.a_d[n * NH + head];
  const float as_n = h2f(G.as2[n * NH + head]);
  float sl = as_n + ad_n;
  sl = (sl > 0.f) ? sl : NEG * sl;
  float wl = __expf(sl);
  uint4 hs = G.h2[(size_t)n * NH + head];
  float denom = wl;
  float4 acc0, acc1;
  acc0.x = wl * hlo(hs.x); acc0.y = wl * hhi(hs.x);
  acc0.z = wl * hlo(hs.y); acc0.w = wl * hhi(hs.y);
  acc1.x = wl * hlo(hs.z); acc1.y = wl * hhi(hs.z);
  acc1.z = wl * hlo(hs.w); acc1.w = wl * hhi(hs.w);
  for (int e = start; e < end; ++e) {
    int src = G.csr[e];
    float s = h2f(G.as2[src * NH + head]) + ad_n;
    s = (s > 0.f) ? s : NEG * s;
    float w = __expf(s);
    uint4 hv = G.h2[(size_t)src * NH + head];
    denom += w;
    acc0.x = fmaf(w, hlo(hv.x), acc0.x); acc0.y = fmaf(w, hhi(hv.x), acc0.y);
    acc0.z = fmaf(w, hlo(hv.y), acc0.z); acc0.w = fmaf(w, hhi(hv.y), acc0.w);
    acc1.x = fmaf(w, hlo(hv.z), acc1.x); acc1.y = fmaf(w, hhi(hv.z), acc1.y);
    acc1.z = fmaf(w, hlo(hv.w), acc1.z); acc1.w = fmaf(w, hhi(hv.w), acc1.w);
  }
  float inv = 1.f / (denom + 1e-16f);
  const float* bp = G.b + head * NC;
  float4 o0, o1;
  o0.x = acc0.x * inv + bp[0]; o0.y = acc0.y * inv + bp[1];
  o0.z = acc0.z * inv + bp[2]; o0.w = acc0.w * inv + bp[3];
  o1.x = acc1.x * inv + bp[4]; o1.y = acc1.y * inv + bp[5];
  o1.z = acc1.z * inv + bp[6]; o1.w = acc1.w * inv + bp[7];
  float4* op = (float4*)(G.out + (size_t)n * HCH + head * NC);
  op[0] = o0; op[1] = o1;
}

// relu(concat) @ fnn_W + fnn_b -> softmax(2). One wave per node.
__global__ __launch_bounds__(256) void k_fnn(const float* __restrict__ o1,
                                             const float* __restrict__ o2,
                                             const float* __restrict__ o3,
                                             const float* __restrict__ fw,
                                             const float* __restrict__ fb,
                                             float* __restrict__ out) {
  const int tid = blockIdx.x * 256 + threadIdx.x;
  const int n = tid >> 6;
  const int lane = tid & 63;
  if (n >= NN) return;
  float acc0 = 0.f, acc1 = 0.f;
  for (int j = lane; j < 3 * HCH; j += 64) {
    const int g = j / HCH;
    const int c = j - g * HCH;
    const float* og = (g == 0) ? o1 : (g == 1) ? o2 : o3;
    float v = og[(size_t)n * HCH + c];
    v = v > 0.f ? v : 0.f;
    acc0 = fmaf(v, fw[2 * j], acc0);
    acc1 = fmaf(v, fw[2 * j + 1], acc1);
  }
  #pragma unroll
  for (int off = 32; off > 0; off >>= 1) {
    acc0 += __shfl_down(acc0, off, 64);
    acc1 += __shfl_down(acc1, off, 64);
  }
  if (lane == 0) {
    float l0 = acc0 + fb[0], l1 = acc1 + fb[1];
    float m = fmaxf(l0, l1);
    float e0 = __expf(l0 - m), e1 = __expf(l1 - m);
    float inv = 1.f / (e0 + e1);
    out[(size_t)n * 2] = e0 * inv;
    out[(size_t)n * 2 + 1] = e1 * inv;
  }
}

extern "C" void kernel_launch(void* const* d_in, const int* in_sizes, int n_in,
                              void* d_out, int out_size, void* d_ws, size_t ws_size,
                              hipStream_t stream) {
  (void)in_sizes; (void)n_in; (void)out_size; (void)ws_size;
  GT t;
  char* w = (char*)d_ws;
  size_t off = 0;
  auto carve = [&](size_t bytes) -> void* {
    void* p = w + off;
    off = (off + bytes + 255) & ~(size_t)255;
    return p;
  };
  for (int g = 0; g < 3; ++g) {
    GP& G = t.g[g];
    G.x  = (const float*)d_in[6 * g + 0];
    G.ei = (const int*)d_in[6 * g + 1];     // harness stores int64 inputs as int32
    G.W  = (const float*)d_in[6 * g + 2];
    G.as = (const float*)d_in[6 * g + 3];
    G.ad = (const float*)d_in[6 * g + 4];
    G.b  = (const float*)d_in[6 * g + 5];
    G.h2   = (uint4*)carve((size_t)NN * NH * 16);
    G.as2  = (unsigned short*)carve((size_t)NN * NH * 2);
    G.a_d  = (float*)carve((size_t)NN * NH * 4);
    G.out  = (float*)carve((size_t)NN * HCH * 4);
    G.hist = (int*)carve((size_t)NN * 4);
    G.offs = (int*)carve((size_t)NN * 4);
    G.chunks = (int*)carve(256);
    G.bcursor = (int*)carve((size_t)NBUCK * 4);
    G.pairs = (unsigned int*)carve((size_t)NE * 4);
    G.csr  = (int*)carve((size_t)NE * 4);
  }
  const float* fw = (const float*)d_in[18];
  const float* fb = (const float*)d_in[19];
  float* outp = (float*)d_out;

  dim3 b256(256, 1, 1);
  k_gemm   <<<dim3((NN + 255) / 256, 1, 3), b256, 0, stream>>>(t);
  k_hist   <<<dim3((NE + 255) / 256, 1, 3), b256, 0, stream>>>(t);
  k_scan1  <<<dim3(NCHUNK, 1, 3), dim3(1024, 1, 1), 0, stream>>>(t);
  k_scan2  <<<dim3(1, 1, 3), dim3(1024, 1, 1), 0, stream>>>(t);
  k_bin    <<<dim3((NE + BCH - 1) / BCH, 1, 3), b256, 0, stream>>>(t);
  k_scat2  <<<dim3(NBUCK, 1, 3), b256, 0, stream>>>(t);
  k_agg    <<<dim3((NN * NH + 255) / 256, 1, 3), b256, 0, stream>>>(t);
  k_fnn    <<<(NN * 64 + 255) / 256, b256, 0, stream>>>(t.g[0].out, t.g[1].out, t.g[2].out, fw, fb, outp);
}

// Round 7
// 569.007 us; speedup vs baseline: 2.2961x; 1.2993x over previous
//
#include <hip/hip_runtime.h>
#include <hip/hip_fp16.h>

#define NN 50000
#define NE 1600000
#define DD 128
#define NH 9
#define NC 8
#define HCH 72
#define NEG 0.2f
#define NBUCK 196      // ceil(50000/256), 256 dst nodes per bucket
#define EPB 8          // edges per thread in k_bin/k_hcnt
#define BCH (256*EPB)  // 2048 edges per block

__device__ __forceinline__ unsigned short f2h(float f) {
  return __half_as_ushort(__float2half_rn(f));
}
__device__ __forceinline__ float h2f(unsigned short u) {
  return __half2float(__ushort_as_half(u));
}
__device__ __forceinline__ float hlo(unsigned u) {
  return __half2float(__ushort_as_half((unsigned short)(u & 0xFFFFu)));
}
__device__ __forceinline__ float hhi(unsigned u) {
  return __half2float(__ushort_as_half((unsigned short)(u >> 16)));
}

struct GP {
  const float* x; const int* ei; const float* W;
  const float* as; const float* ad; const float* b;
  uint4* h2;                // [NN*9] uint4: 8 fp16 channels per (node,head)
  unsigned short* as2;      // [NN*9] fp16 src-attention scores
  float* a_d; float* out;
  int* offs;                // [NN] global exclusive scan of in-degree (filled by k_scat2)
  int* bcount;              // [NBUCK] bucket sizes
  int* bcursor;             // [NBUCK] write cursors for k_bin
  int* bstart;              // [NBUCK+1] bucket base offsets
  unsigned int* pairs; int* csr;
};
struct GT { GP g[3]; };

// h = x@W: one thread per NODE, all 72 channels in registers.
// W staged in LDS (wave-uniform broadcast reads); x read as 32 float4/thread.
// Block 0 also zeroes bcount (runs before k_hcnt in stream order).
__global__ __launch_bounds__(256) void k_gemm(GT t) {
  const GP G = t.g[blockIdx.z];
  __shared__ float Wl[DD * HCH];   // 36 KB
  const int tid = threadIdx.x;
  if (blockIdx.x == 0 && tid < NBUCK) G.bcount[tid] = 0;
  {
    const float4* Wg = (const float4*)G.W;
    float4* Wd = (float4*)Wl;
    #pragma unroll
    for (int i = 0; i < 9; ++i) Wd[tid + 256 * i] = Wg[tid + 256 * i];  // 2304 = 256*9
  }
  const int n = blockIdx.x * 256 + tid;
  __syncthreads();
  if (n >= NN) return;

  float4 acc[18];
  #pragma unroll
  for (int i = 0; i < 18; ++i) acc[i] = make_float4(0.f, 0.f, 0.f, 0.f);
  const float4* x4 = (const float4*)(G.x + (size_t)n * DD);

  for (int k4 = 0; k4 < DD / 4; ++k4) {
    const float4 xv = x4[k4];
    const float* w0 = &Wl[(k4 * 4) * HCH];
    #pragma unroll
    for (int kk = 0; kk < 4; ++kk) {
      const float xk = (kk == 0) ? xv.x : (kk == 1) ? xv.y : (kk == 2) ? xv.z : xv.w;
      const float4* wr = (const float4*)(w0 + kk * HCH);
      #pragma unroll
      for (int c4 = 0; c4 < 18; ++c4) {
        float4 wv = wr[c4];                       // wave-uniform LDS broadcast
        acc[c4].x = fmaf(xk, wv.x, acc[c4].x);
        acc[c4].y = fmaf(xk, wv.y, acc[c4].y);
        acc[c4].z = fmaf(xk, wv.z, acc[c4].z);
        acc[c4].w = fmaf(xk, wv.w, acc[c4].w);
      }
    }
  }

  // epilogue: per head, attention dots + fp16 pack
  #pragma unroll
  for (int hd = 0; hd < NH; ++hd) {
    const float4 a0 = acc[2 * hd];
    const float4 a1 = acc[2 * hd + 1];
    const float4 As0 = *(const float4*)(G.as + hd * NC);
    const float4 As1 = *(const float4*)(G.as + hd * NC + 4);
    const float4 Ad0 = *(const float4*)(G.ad + hd * NC);
    const float4 Ad1 = *(const float4*)(G.ad + hd * NC + 4);
    float ssrc = a0.x*As0.x + a0.y*As0.y + a0.z*As0.z + a0.w*As0.w
               + a1.x*As1.x + a1.y*As1.y + a1.z*As1.z + a1.w*As1.w;
    float sdst = a0.x*Ad0.x + a0.y*Ad0.y + a0.z*Ad0.z + a0.w*Ad0.w
               + a1.x*Ad1.x + a1.y*Ad1.y + a1.z*Ad1.z + a1.w*Ad1.w;
    G.as2[n * NH + hd] = f2h(ssrc);
    G.a_d[n * NH + hd] = sdst;
    uint4 hv;
    hv.x = (unsigned)f2h(a0.x) | ((unsigned)f2h(a0.y) << 16);
    hv.y = (unsigned)f2h(a0.z) | ((unsigned)f2h(a0.w) << 16);
    hv.z = (unsigned)f2h(a1.x) | ((unsigned)f2h(a1.y) << 16);
    hv.w = (unsigned)f2h(a1.z) | ((unsigned)f2h(a1.w) << 16);
    G.h2[(size_t)n * NH + hd] = hv;
  }
}

// bucket-level histogram: LDS 196 bins per 2048-edge block, flush via 196 atomics
__global__ __launch_bounds__(256) void k_hcnt(GT t) {
  const GP G = t.g[blockIdx.z];
  __shared__ int lh[NBUCK];
  const int tid = threadIdx.x;
  const int e0 = blockIdx.x * BCH;
  for (int i = tid; i < NBUCK; i += 256) lh[i] = 0;
  __syncthreads();
  #pragma unroll
  for (int k = 0; k < EPB; ++k) {
    const int e = e0 + k * 256 + tid;
    if (e < NE) atomicAdd(&lh[G.ei[NE + e] >> 8], 1);
  }
  __syncthreads();
  for (int i = tid; i < NBUCK; i += 256) {
    int c = lh[i];
    if (c) atomicAdd(&G.bcount[i], c);
  }
}

// scan 196 bucket counts -> bstart / bcursor
__global__ __launch_bounds__(256) void k_scanb(GT t) {
  const GP G = t.g[blockIdx.z];
  __shared__ int s[256];
  const int tid = threadIdx.x;
  int v = (tid < NBUCK) ? G.bcount[tid] : 0;
  s[tid] = v;
  __syncthreads();
  for (int off = 1; off < 256; off <<= 1) {
    int u = (tid >= off) ? s[tid - off] : 0;
    __syncthreads();
    s[tid] += u;
    __syncthreads();
  }
  if (tid < NBUCK) {
    int excl = s[tid] - v;
    G.bcursor[tid] = excl;
    G.bstart[tid] = excl;
  }
  if (tid == 0) G.bstart[NBUCK] = NE;
}

// phase 1: bin edges into 196 dense per-bucket runs of packed (dst_local<<16|src)
__global__ __launch_bounds__(256) void k_bin(GT t) {
  const GP G = t.g[blockIdx.z];
  __shared__ int lh[NBUCK];    // per-block bucket histogram
  __shared__ int lbase[NBUCK]; // reserved global base per bucket
  __shared__ int lcur[NBUCK];  // local cursor
  const int tid = threadIdx.x;
  const int e0 = blockIdx.x * BCH;
  for (int i = tid; i < NBUCK; i += 256) lh[i] = 0;
  __syncthreads();
  int dsts[EPB], srcs[EPB];
  #pragma unroll
  for (int k = 0; k < EPB; ++k) {
    const int e = e0 + k * 256 + tid;
    if (e < NE) {
      int dst = G.ei[NE + e];
      srcs[k] = G.ei[e];
      dsts[k] = dst;
      atomicAdd(&lh[dst >> 8], 1);
    } else dsts[k] = -1;
  }
  __syncthreads();
  for (int i = tid; i < NBUCK; i += 256) {
    int c = lh[i];
    lbase[i] = c ? atomicAdd(&G.bcursor[i], c) : 0;
    lcur[i] = 0;
  }
  __syncthreads();
  #pragma unroll
  for (int k = 0; k < EPB; ++k) {
    if (dsts[k] >= 0) {
      int b = dsts[k] >> 8;
      int pos = lbase[b] + atomicAdd(&lcur[b], 1);
      G.pairs[pos] = (unsigned int)srcs[k] | ((unsigned int)(dsts[k] & 255) << 16);
    }
  }
}

// phase 2: one block per bucket. Pass 1: per-dst LDS count + scan -> global offs.
// Pass 2: scatter src into the bucket's csr window (one XCD's L2).
__global__ __launch_bounds__(256) void k_scat2(GT t) {
  const GP G = t.g[blockIdx.z];
  const int b = blockIdx.x;
  const int d0 = b << 8;
  __shared__ int cnt[256];
  __shared__ int cur[256];
  const int tid = threadIdx.x;
  const int estart = G.bstart[b];
  const int eend = G.bstart[b + 1];
  cnt[tid] = 0;
  __syncthreads();
  for (int e = estart + tid; e < eend; e += 256) {
    atomicAdd(&cnt[G.pairs[e] >> 16], 1);
  }
  __syncthreads();
  // exclusive scan of cnt[256]
  int v = cnt[tid];
  int run = v;
  for (int off = 1; off < 256; off <<= 1) {
    int u = (tid >= off) ? cnt[tid - off] : 0;   // read pre-update values safely:
    __syncthreads();
    run += u;
    cnt[tid] = run;
    __syncthreads();
  }
  int excl = run - v;
  int base = estart + excl;
  if (d0 + tid < NN) G.offs[d0 + tid] = base;
  cur[tid] = base;
  __syncthreads();
  for (int e = estart + tid; e < eend; e += 256) {
    unsigned int p = G.pairs[e];
    int pos = atomicAdd(&cur[p >> 16], 1);
    G.csr[pos] = (int)(p & 0xFFFFu);
  }
}

// gather aggregation over fp16 h2/as2: thread (dst,head) walks incoming edges.
__global__ __launch_bounds__(256) void k_agg(GT t) {
  const GP G = t.g[blockIdx.z];
  const int gid = blockIdx.x * 256 + threadIdx.x;
  if (gid >= NN * NH) return;
  const int n = gid / NH;
  const int head = gid - n * NH;
  const int start = G.offs[n];
  const int end = (n + 1 < NN) ? G.offs[n + 1] : NE;
  const float ad_n = G.a_d[n * NH + head];
  const float as_n = h2f(G.as2[n * NH + head]);
  float sl = as_n + ad_n;
  sl = (sl > 0.f) ? sl : NEG * sl;
  float wl = __expf(sl);
  uint4 hs = G.h2[(size_t)n * NH + head];
  float denom = wl;
  float4 acc0, acc1;
  acc0.x = wl * hlo(hs.x); acc0.y = wl * hhi(hs.x);
  acc0.z = wl * hlo(hs.y); acc0.w = wl * hhi(hs.y);
  acc1.x = wl * hlo(hs.z); acc1.y = wl * hhi(hs.z);
  acc1.z = wl * hlo(hs.w); acc1.w = wl * hhi(hs.w);
  for (int e = start; e < end; ++e) {
    int src = G.csr[e];
    float s = h2f(G.as2[src * NH + head]) + ad_n;
    s = (s > 0.f) ? s : NEG * s;
    float w = __expf(s);
    uint4 hv = G.h2[(size_t)src * NH + head];
    denom += w;
    acc0.x = fmaf(w, hlo(hv.x), acc0.x); acc0.y = fmaf(w, hhi(hv.x), acc0.y);
    acc0.z = fmaf(w, hlo(hv.y), acc0.z); acc0.w = fmaf(w, hhi(hv.y), acc0.w);
    acc1.x = fmaf(w, hlo(hv.z), acc1.x); acc1.y = fmaf(w, hhi(hv.z), acc1.y);
    acc1.z = fmaf(w, hlo(hv.w), acc1.z); acc1.w = fmaf(w, hhi(hv.w), acc1.w);
  }
  float inv = 1.f / (denom + 1e-16f);
  const float* bp = G.b + head * NC;
  float4 o0, o1;
  o0.x = acc0.x * inv + bp[0]; o0.y = acc0.y * inv + bp[1];
  o0.z = acc0.z * inv + bp[2]; o0.w = acc0.w * inv + bp[3];
  o1.x = acc1.x * inv + bp[4]; o1.y = acc1.y * inv + bp[5];
  o1.z = acc1.z * inv + bp[6]; o1.w = acc1.w * inv + bp[7];
  float4* op = (float4*)(G.out + (size_t)n * HCH + head * NC);
  op[0] = o0; op[1] = o1;
}

// relu(concat) @ fnn_W + fnn_b -> softmax(2). One wave per node.
__global__ __launch_bounds__(256) void k_fnn(const float* __restrict__ o1,
                                             const float* __restrict__ o2,
                                             const float* __restrict__ o3,
                                             const float* __restrict__ fw,
                                             const float* __restrict__ fb,
                                             float* __restrict__ out) {
  const int tid = blockIdx.x * 256 + threadIdx.x;
  const int n = tid >> 6;
  const int lane = tid & 63;
  if (n >= NN) return;
  float acc0 = 0.f, acc1 = 0.f;
  for (int j = lane; j < 3 * HCH; j += 64) {
    const int g = j / HCH;
    const int c = j - g * HCH;
    const float* og = (g == 0) ? o1 : (g == 1) ? o2 : o3;
    float v = og[(size_t)n * HCH + c];
    v = v > 0.f ? v : 0.f;
    acc0 = fmaf(v, fw[2 * j], acc0);
    acc1 = fmaf(v, fw[2 * j + 1], acc1);
  }
  #pragma unroll
  for (int off = 32; off > 0; off >>= 1) {
    acc0 += __shfl_down(acc0, off, 64);
    acc1 += __shfl_down(acc1, off, 64);
  }
  if (lane == 0) {
    float l0 = acc0 + fb[0], l1 = acc1 + fb[1];
    float m = fmaxf(l0, l1);
    float e0 = __expf(l0 - m), e1 = __expf(l1 - m);
    float inv = 1.f / (e0 + e1);
    out[(size_t)n * 2] = e0 * inv;
    out[(size_t)n * 2 + 1] = e1 * inv;
  }
}

extern "C" void kernel_launch(void* const* d_in, const int* in_sizes, int n_in,
                              void* d_out, int out_size, void* d_ws, size_t ws_size,
                              hipStream_t stream) {
  (void)in_sizes; (void)n_in; (void)out_size; (void)ws_size;
  GT t;
  char* w = (char*)d_ws;
  size_t off = 0;
  auto carve = [&](size_t bytes) -> void* {
    void* p = w + off;
    off = (off + bytes + 255) & ~(size_t)255;
    return p;
  };
  for (int g = 0; g < 3; ++g) {
    GP& G = t.g[g];
    G.x  = (const float*)d_in[6 * g + 0];
    G.ei = (const int*)d_in[6 * g + 1];     // harness stores int64 inputs as int32
    G.W  = (const float*)d_in[6 * g + 2];
    G.as = (const float*)d_in[6 * g + 3];
    G.ad = (const float*)d_in[6 * g + 4];
    G.b  = (const float*)d_in[6 * g + 5];
    G.h2   = (uint4*)carve((size_t)NN * NH * 16);
    G.as2  = (unsigned short*)carve((size_t)NN * NH * 2);
    G.a_d  = (float*)carve((size_t)NN * NH * 4);
    G.out  = (float*)carve((size_t)NN * HCH * 4);
    G.offs = (int*)carve((size_t)NN * 4);
    G.bcount  = (int*)carve((size_t)NBUCK * 4);
    G.bcursor = (int*)carve((size_t)NBUCK * 4);
    G.bstart  = (int*)carve((size_t)(NBUCK + 1) * 4);
    G.pairs = (unsigned int*)carve((size_t)NE * 4);
    G.csr  = (int*)carve((size_t)NE * 4);
  }
  const float* fw = (const float*)d_in[18];
  const float* fb = (const float*)d_in[19];
  float* outp = (float*)d_out;

  dim3 b256(256, 1, 1);
  k_gemm   <<<dim3((NN + 255) / 256, 1, 3), b256, 0, stream>>>(t);
  k_hcnt   <<<dim3((NE + BCH - 1) / BCH, 1, 3), b256, 0, stream>>>(t);
  k_scanb  <<<dim3(1, 1, 3), b256, 0, stream>>>(t);
  k_bin    <<<dim3((NE + BCH - 1) / BCH, 1, 3), b256, 0, stream>>>(t);
  k_scat2  <<<dim3(NBUCK, 1, 3), b256, 0, stream>>>(t);
  k_agg    <<<dim3((NN * NH + 255) / 256, 1, 3), b256, 0, stream>>>(t);
  k_fnn    <<<(NN * 64 + 255) / 256, b256, 0, stream>>>(t.g[0].out, t.g[1].out, t.g[2].out, fw, fb, outp);
}

// Round 8
// 544.361 us; speedup vs baseline: 2.4000x; 1.0453x over previous
//
#include <hip/hip_runtime.h>
#include <hip/hip_fp16.h>

#define NN 50000
#define NE 1600000
#define DD 128
#define NH 9
#define NC 8
#define HCH 72
#define NEG 0.2f
#define NBUCK 196      // ceil(50000/256), 256 dst nodes per bucket
#define NSEG 8         // src segments of 8192 nodes (only 0..6 non-empty)
#define NBIN (NBUCK*NSEG)
#define EPB 8          // edges per thread in k_bin/k_hcnt
#define BCH (256*EPB)  // 2048 edges per block

__device__ __forceinline__ unsigned short f2h(float f) {
  return __half_as_ushort(__float2half_rn(f));
}
__device__ __forceinline__ float h2f(unsigned short u) {
  return __half2float(__ushort_as_half(u));
}
__device__ __forceinline__ float hlo(unsigned u) {
  return __half2float(__ushort_as_half((unsigned short)(u & 0xFFFFu)));
}
__device__ __forceinline__ float hhi(unsigned u) {
  return __half2float(__ushort_as_half((unsigned short)(u >> 16)));
}

struct GP {
  const float* x; const int* ei; const float* W;
  const float* as; const float* ad; const float* b;
  uint4* h2;                // [NN*9] uint4: 8 fp16 channels per (node,head)
  unsigned short* as2;      // [NN*9] fp16 src-attention scores
  float* a_d; float* out;
  int* offs;                // [NN] global exclusive scan of in-degree (filled by k_scat2)
  int* bcount;              // [NBIN] (bucket,seg) sizes
  int* bcursor;             // [NBIN] write cursors for k_bin
  int* bstart;              // [NBIN+1] bin base offsets
  unsigned int* pairs; int* csr;
};
struct GT { GP g[3]; };

// h = x@W: one thread per NODE, all 72 channels in registers.
// W staged in LDS (wave-uniform broadcast reads). Block 0 zeroes bcount.
__global__ __launch_bounds__(256) void k_gemm(GT t) {
  const GP G = t.g[blockIdx.z];
  __shared__ float Wl[DD * HCH];   // 36 KB
  const int tid = threadIdx.x;
  if (blockIdx.x == 0) {
    for (int i = tid; i < NBIN; i += 256) G.bcount[i] = 0;
  }
  {
    const float4* Wg = (const float4*)G.W;
    float4* Wd = (float4*)Wl;
    #pragma unroll
    for (int i = 0; i < 9; ++i) Wd[tid + 256 * i] = Wg[tid + 256 * i];  // 2304 = 256*9
  }
  const int n = blockIdx.x * 256 + tid;
  __syncthreads();
  if (n >= NN) return;

  float4 acc[18];
  #pragma unroll
  for (int i = 0; i < 18; ++i) acc[i] = make_float4(0.f, 0.f, 0.f, 0.f);
  const float4* x4 = (const float4*)(G.x + (size_t)n * DD);

  for (int k4 = 0; k4 < DD / 4; ++k4) {
    const float4 xv = x4[k4];
    const float* w0 = &Wl[(k4 * 4) * HCH];
    #pragma unroll
    for (int kk = 0; kk < 4; ++kk) {
      const float xk = (kk == 0) ? xv.x : (kk == 1) ? xv.y : (kk == 2) ? xv.z : xv.w;
      const float4* wr = (const float4*)(w0 + kk * HCH);
      #pragma unroll
      for (int c4 = 0; c4 < 18; ++c4) {
        float4 wv = wr[c4];                       // wave-uniform LDS broadcast
        acc[c4].x = fmaf(xk, wv.x, acc[c4].x);
        acc[c4].y = fmaf(xk, wv.y, acc[c4].y);
        acc[c4].z = fmaf(xk, wv.z, acc[c4].z);
        acc[c4].w = fmaf(xk, wv.w, acc[c4].w);
      }
    }
  }

  #pragma unroll
  for (int hd = 0; hd < NH; ++hd) {
    const float4 a0 = acc[2 * hd];
    const float4 a1 = acc[2 * hd + 1];
    const float4 As0 = *(const float4*)(G.as + hd * NC);
    const float4 As1 = *(const float4*)(G.as + hd * NC + 4);
    const float4 Ad0 = *(const float4*)(G.ad + hd * NC);
    const float4 Ad1 = *(const float4*)(G.ad + hd * NC + 4);
    float ssrc = a0.x*As0.x + a0.y*As0.y + a0.z*As0.z + a0.w*As0.w
               + a1.x*As1.x + a1.y*As1.y + a1.z*As1.z + a1.w*As1.w;
    float sdst = a0.x*Ad0.x + a0.y*Ad0.y + a0.z*Ad0.z + a0.w*Ad0.w
               + a1.x*Ad1.x + a1.y*Ad1.y + a1.z*Ad1.z + a1.w*Ad1.w;
    G.as2[n * NH + hd] = f2h(ssrc);
    G.a_d[n * NH + hd] = sdst;
    uint4 hv;
    hv.x = (unsigned)f2h(a0.x) | ((unsigned)f2h(a0.y) << 16);
    hv.y = (unsigned)f2h(a0.z) | ((unsigned)f2h(a0.w) << 16);
    hv.z = (unsigned)f2h(a1.x) | ((unsigned)f2h(a1.y) << 16);
    hv.w = (unsigned)f2h(a1.z) | ((unsigned)f2h(a1.w) << 16);
    G.h2[(size_t)n * NH + hd] = hv;
  }
}

// (bucket,seg)-level histogram: LDS 1568 bins per 2048-edge block
__global__ __launch_bounds__(256) void k_hcnt(GT t) {
  const GP G = t.g[blockIdx.z];
  __shared__ int lh[NBIN];
  const int tid = threadIdx.x;
  const int e0 = blockIdx.x * BCH;
  for (int i = tid; i < NBIN; i += 256) lh[i] = 0;
  __syncthreads();
  #pragma unroll
  for (int k = 0; k < EPB; ++k) {
    const int e = e0 + k * 256 + tid;
    if (e < NE) {
      int dst = G.ei[NE + e];
      int src = G.ei[e];
      atomicAdd(&lh[((dst >> 8) << 3) | (src >> 13)], 1);
    }
  }
  __syncthreads();
  for (int i = tid; i < NBIN; i += 256) {
    int c = lh[i];
    if (c) atomicAdd(&G.bcount[i], c);
  }
}

// scan NBIN bucket-seg counts -> bstart / bcursor (one block, chunked with carry)
__global__ __launch_bounds__(256) void k_scanb(GT t) {
  const GP G = t.g[blockIdx.z];
  __shared__ int s[256];
  __shared__ int carry;
  const int tid = threadIdx.x;
  if (tid == 0) carry = 0;
  __syncthreads();
  for (int c0 = 0; c0 < NBIN; c0 += 256) {
    const int i = c0 + tid;
    int v = (i < NBIN) ? G.bcount[i] : 0;
    s[tid] = v;
    __syncthreads();
    for (int off = 1; off < 256; off <<= 1) {
      int u = (tid >= off) ? s[tid - off] : 0;
      __syncthreads();
      s[tid] += u;
      __syncthreads();
    }
    if (i < NBIN) {
      int excl = carry + s[tid] - v;
      G.bcursor[i] = excl;
      G.bstart[i] = excl;
    }
    __syncthreads();
    if (tid == 0) carry += s[255];
    __syncthreads();
  }
  if (tid == 0) G.bstart[NBIN] = NE;
}

// phase 1: bin edges into (bucket,seg) runs of packed (dst_local<<16 | src)
__global__ __launch_bounds__(256) void k_bin(GT t) {
  const GP G = t.g[blockIdx.z];
  __shared__ int lh[NBIN];
  __shared__ int lbase[NBIN];
  __shared__ int lcur[NBIN];
  const int tid = threadIdx.x;
  const int e0 = blockIdx.x * BCH;
  for (int i = tid; i < NBIN; i += 256) lh[i] = 0;
  __syncthreads();
  int bins[EPB], srcs[EPB], dls[EPB];
  #pragma unroll
  for (int k = 0; k < EPB; ++k) {
    const int e = e0 + k * 256 + tid;
    if (e < NE) {
      int dst = G.ei[NE + e];
      int src = G.ei[e];
      srcs[k] = src;
      dls[k] = dst & 255;
      bins[k] = ((dst >> 8) << 3) | (src >> 13);
      atomicAdd(&lh[bins[k]], 1);
    } else bins[k] = -1;
  }
  __syncthreads();
  for (int i = tid; i < NBIN; i += 256) {
    int c = lh[i];
    lbase[i] = c ? atomicAdd(&G.bcursor[i], c) : 0;
    lcur[i] = 0;
  }
  __syncthreads();
  #pragma unroll
  for (int k = 0; k < EPB; ++k) {
    if (bins[k] >= 0) {
      int pos = lbase[bins[k]] + atomicAdd(&lcur[bins[k]], 1);
      G.pairs[pos] = (unsigned int)srcs[k] | ((unsigned int)dls[k] << 16);
    }
  }
}

// phase 2: one block per bucket. Pass 1: per-dst LDS count + scan -> global offs.
// Pass 2: scatter src into csr. Reading the bucket range in order preserves
// the src-segment grouping inside each dst's run.
__global__ __launch_bounds__(256) void k_scat2(GT t) {
  const GP G = t.g[blockIdx.z];
  const int b = blockIdx.x;
  const int d0 = b << 8;
  __shared__ int cnt[256];
  __shared__ int cur[256];
  const int tid = threadIdx.x;
  const int estart = G.bstart[b * NSEG];
  const int eend = G.bstart[(b + 1) * NSEG];
  cnt[tid] = 0;
  __syncthreads();
  for (int e = estart + tid; e < eend; e += 256) {
    atomicAdd(&cnt[G.pairs[e] >> 16], 1);
  }
  __syncthreads();
  int v = cnt[tid];
  int run = v;
  for (int off = 1; off < 256; off <<= 1) {
    int u = (tid >= off) ? cnt[tid - off] : 0;
    __syncthreads();
    run += u;
    cnt[tid] = run;
    __syncthreads();
  }
  int excl = run - v;
  int base = estart + excl;
  if (d0 + tid < NN) G.offs[d0 + tid] = base;
  cur[tid] = base;
  __syncthreads();
  for (int e = estart + tid; e < eend; e += 256) {
    unsigned int p = G.pairs[e];
    int pos = atomicAdd(&cur[p >> 16], 1);
    G.csr[pos] = (int)(p & 0xFFFFu);
  }
}

// gather aggregation over fp16 h2/as2, 2-edge unrolled.
__global__ __launch_bounds__(256) void k_agg(GT t) {
  const GP G = t.g[blockIdx.z];
  const int gid = blockIdx.x * 256 + threadIdx.x;
  if (gid >= NN * NH) return;
  const int n = gid / NH;
  const int head = gid - n * NH;
  const int start = G.offs[n];
  const int end = (n + 1 < NN) ? G.offs[n + 1] : NE;
  const float ad_n = G.a_d[n * NH + head];
  const float as_n = h2f(G.as2[n * NH + head]);
  float sl = as_n + ad_n;
  sl = (sl > 0.f) ? sl : NEG * sl;
  float wl = __expf(sl);
  uint4 hs = G.h2[(size_t)n * NH + head];
  float denom = wl;
  float4 acc0, acc1;
  acc0.x = wl * hlo(hs.x); acc0.y = wl * hhi(hs.x);
  acc0.z = wl * hlo(hs.y); acc0.w = wl * hhi(hs.y);
  acc1.x = wl * hlo(hs.z); acc1.y = wl * hhi(hs.z);
  acc1.z = wl * hlo(hs.w); acc1.w = wl * hhi(hs.w);
  int e = start;
  for (; e + 2 <= end; e += 2) {
    int s0 = G.csr[e];
    int s1 = G.csr[e + 1];
    float t0 = h2f(G.as2[s0 * NH + head]) + ad_n;
    float t1 = h2f(G.as2[s1 * NH + head]) + ad_n;
    uint4 v0 = G.h2[(size_t)s0 * NH + head];
    uint4 v1 = G.h2[(size_t)s1 * NH + head];
    t0 = (t0 > 0.f) ? t0 : NEG * t0;
    t1 = (t1 > 0.f) ? t1 : NEG * t1;
    float w0 = __expf(t0);
    float w1 = __expf(t1);
    denom += w0 + w1;
    acc0.x = fmaf(w0, hlo(v0.x), acc0.x); acc0.y = fmaf(w0, hhi(v0.x), acc0.y);
    acc0.z = fmaf(w0, hlo(v0.y), acc0.z); acc0.w = fmaf(w0, hhi(v0.y), acc0.w);
    acc1.x = fmaf(w0, hlo(v0.z), acc1.x); acc1.y = fmaf(w0, hhi(v0.z), acc1.y);
    acc1.z = fmaf(w0, hlo(v0.w), acc1.z); acc1.w = fmaf(w0, hhi(v0.w), acc1.w);
    acc0.x = fmaf(w1, hlo(v1.x), acc0.x); acc0.y = fmaf(w1, hhi(v1.x), acc0.y);
    acc0.z = fmaf(w1, hlo(v1.y), acc0.z); acc0.w = fmaf(w1, hhi(v1.y), acc0.w);
    acc1.x = fmaf(w1, hlo(v1.z), acc1.x); acc1.y = fmaf(w1, hhi(v1.z), acc1.y);
    acc1.z = fmaf(w1, hlo(v1.w), acc1.z); acc1.w = fmaf(w1, hhi(v1.w), acc1.w);
  }
  if (e < end) {
    int src = G.csr[e];
    float s = h2f(G.as2[src * NH + head]) + ad_n;
    s = (s > 0.f) ? s : NEG * s;
    float w = __expf(s);
    uint4 hv = G.h2[(size_t)src * NH + head];
    denom += w;
    acc0.x = fmaf(w, hlo(hv.x), acc0.x); acc0.y = fmaf(w, hhi(hv.x), acc0.y);
    acc0.z = fmaf(w, hlo(hv.y), acc0.z); acc0.w = fmaf(w, hhi(hv.y), acc0.w);
    acc1.x = fmaf(w, hlo(hv.z), acc1.x); acc1.y = fmaf(w, hhi(hv.z), acc1.y);
    acc1.z = fmaf(w, hlo(hv.w), acc1.z); acc1.w = fmaf(w, hhi(hv.w), acc1.w);
  }
  float inv = 1.f / (denom + 1e-16f);
  const float* bp = G.b + head * NC;
  float4 o0, o1;
  o0.x = acc0.x * inv + bp[0]; o0.y = acc0.y * inv + bp[1];
  o0.z = acc0.z * inv + bp[2]; o0.w = acc0.w * inv + bp[3];
  o1.x = acc1.x * inv + bp[4]; o1.y = acc1.y * inv + bp[5];
  o1.z = acc1.z * inv + bp[6]; o1.w = acc1.w * inv + bp[7];
  float4* op = (float4*)(G.out + (size_t)n * HCH + head * NC);
  op[0] = o0; op[1] = o1;
}

// relu(concat) @ fnn_W + fnn_b -> softmax(2). One wave per node.
__global__ __launch_bounds__(256) void k_fnn(const float* __restrict__ o1,
                                             const float* __restrict__ o2,
                                             const float* __restrict__ o3,
                                             const float* __restrict__ fw,
                                             const float* __restrict__ fb,
                                             float* __restrict__ out) {
  const int tid = blockIdx.x * 256 + threadIdx.x;
  const int n = tid >> 6;
  const int lane = tid & 63;
  if (n >= NN) return;
  float acc0 = 0.f, acc1 = 0.f;
  for (int j = lane; j < 3 * HCH; j += 64) {
    const int g = j / HCH;
    const int c = j - g * HCH;
    const float* og = (g == 0) ? o1 : (g == 1) ? o2 : o3;
    float v = og[(size_t)n * HCH + c];
    v = v > 0.f ? v : 0.f;
    acc0 = fmaf(v, fw[2 * j], acc0);
    acc1 = fmaf(v, fw[2 * j + 1], acc1);
  }
  #pragma unroll
  for (int off = 32; off > 0; off >>= 1) {
    acc0 += __shfl_down(acc0, off, 64);
    acc1 += __shfl_down(acc1, off, 64);
  }
  if (lane == 0) {
    float l0 = acc0 + fb[0], l1 = acc1 + fb[1];
    float m = fmaxf(l0, l1);
    float e0 = __expf(l0 - m), e1 = __expf(l1 - m);
    float inv = 1.f / (e0 + e1);
    out[(size_t)n * 2] = e0 * inv;
    out[(size_t)n * 2 + 1] = e1 * inv;
  }
}

extern "C" void kernel_launch(void* const* d_in, const int* in_sizes, int n_in,
                              void* d_out, int out_size, void* d_ws, size_t ws_size,
                              hipStream_t stream) {
  (void)in_sizes; (void)n_in; (void)out_size; (void)ws_size;
  GT t;
  char* w = (char*)d_ws;
  size_t off = 0;
  auto carve = [&](size_t bytes) -> void* {
    void* p = w + off;
    off = (off + bytes + 255) & ~(size_t)255;
    return p;
  };
  for (int g = 0; g < 3; ++g) {
    GP& G = t.g[g];
    G.x  = (const float*)d_in[6 * g + 0];
    G.ei = (const int*)d_in[6 * g + 1];     // harness stores int64 inputs as int32
    G.W  = (const float*)d_in[6 * g + 2];
    G.as = (const float*)d_in[6 * g + 3];
    G.ad = (const float*)d_in[6 * g + 4];
    G.b  = (const float*)d_in[6 * g + 5];
    G.h2   = (uint4*)carve((size_t)NN * NH * 16);
    G.as2  = (unsigned short*)carve((size_t)NN * NH * 2);
    G.a_d  = (float*)carve((size_t)NN * NH * 4);
    G.out  = (float*)carve((size_t)NN * HCH * 4);
    G.offs = (int*)carve((size_t)NN * 4);
    G.bcount  = (int*)carve((size_t)NBIN * 4);
    G.bcursor = (int*)carve((size_t)NBIN * 4);
    G.bstart  = (int*)carve((size_t)(NBIN + 1) * 4);
    G.pairs = (unsigned int*)carve((size_t)NE * 4);
    G.csr  = (int*)carve((size_t)NE * 4);
  }
  const float* fw = (const float*)d_in[18];
  const float* fb = (const float*)d_in[19];
  float* outp = (float*)d_out;

  dim3 b256(256, 1, 1);
  k_gemm   <<<dim3((NN + 255) / 256, 1, 3), b256, 0, stream>>>(t);
  k_hcnt   <<<dim3((NE + BCH - 1) / BCH, 1, 3), b256, 0, stream>>>(t);
  k_scanb  <<<dim3(1, 1, 3), b256, 0, stream>>>(t);
  k_bin    <<<dim3((NE + BCH - 1) / BCH, 1, 3), b256, 0, stream>>>(t);
  k_scat2  <<<dim3(NBUCK, 1, 3), b256, 0, stream>>>(t);
  k_agg    <<<dim3((NN * NH + 255) / 256, 1, 3), b256, 0, stream>>>(t);
  k_fnn    <<<(NN * 64 + 255) / 256, b256, 0, stream>>>(t.g[0].out, t.g[1].out, t.g[2].out, fw, fb, outp);
}

// Round 9
// 529.273 us; speedup vs baseline: 2.4685x; 1.0285x over previous
//
#include <hip/hip_runtime.h>
#include <hip/hip_fp16.h>

#define NN 50000
#define NE 1600000
#define DD 128
#define NH 9
#define NC 8
#define HCH 72
#define NEG 0.2f
#define NBUCK 196      // ceil(50000/256), 256 dst nodes per bucket
#define NSEG 16        // src segments of 4096 nodes (only 0..12 non-empty)
#define EPB 8          // edges per thread in k_bin/k_hcnt
#define BCH (256*EPB)  // 2048 edges per block

__device__ __forceinline__ unsigned short f2h(float f) {
  return __half_as_ushort(__float2half_rn(f));
}
__device__ __forceinline__ float h2f(unsigned short u) {
  return __half2float(__ushort_as_half(u));
}
__device__ __forceinline__ float hlo(unsigned u) {
  return __half2float(__ushort_as_half((unsigned short)(u & 0xFFFFu)));
}
__device__ __forceinline__ float hhi(unsigned u) {
  return __half2float(__ushort_as_half((unsigned short)(u >> 16)));
}

struct GP {
  const float* x; const int* ei; const float* W;
  const float* as; const float* ad; const float* b;
  uint4* h2;                // [NN*9] uint4: 8 fp16 channels per (node,head)
  unsigned short* as2;      // [NN*9] fp16 src-attention scores
  float* a_d; float* out;
  int* offs2;               // [NBUCK*256*16+1] per-(node,seg) csr offsets
  int* bcount;              // [NBUCK]
  int* bcursor;             // [NBUCK]
  int* bstart;              // [NBUCK+1]
  unsigned int* pairs; int* csr;
};
struct GT { GP g[3]; };

// h = x@W: one thread per NODE, all 72 channels in registers.
// W staged in LDS (wave-uniform broadcast reads). Block 0 zeroes bcount.
__global__ __launch_bounds__(256) void k_gemm(GT t) {
  const GP G = t.g[blockIdx.z];
  __shared__ float Wl[DD * HCH];   // 36 KB
  const int tid = threadIdx.x;
  if (blockIdx.x == 0 && tid < NBUCK) G.bcount[tid] = 0;
  {
    const float4* Wg = (const float4*)G.W;
    float4* Wd = (float4*)Wl;
    #pragma unroll
    for (int i = 0; i < 9; ++i) Wd[tid + 256 * i] = Wg[tid + 256 * i];  // 2304 = 256*9
  }
  const int n = blockIdx.x * 256 + tid;
  __syncthreads();
  if (n >= NN) return;

  float4 acc[18];
  #pragma unroll
  for (int i = 0; i < 18; ++i) acc[i] = make_float4(0.f, 0.f, 0.f, 0.f);
  const float4* x4 = (const float4*)(G.x + (size_t)n * DD);

  for (int k4 = 0; k4 < DD / 4; ++k4) {
    const float4 xv = x4[k4];
    const float* w0 = &Wl[(k4 * 4) * HCH];
    #pragma unroll
    for (int kk = 0; kk < 4; ++kk) {
      const float xk = (kk == 0) ? xv.x : (kk == 1) ? xv.y : (kk == 2) ? xv.z : xv.w;
      const float4* wr = (const float4*)(w0 + kk * HCH);
      #pragma unroll
      for (int c4 = 0; c4 < 18; ++c4) {
        float4 wv = wr[c4];                       // wave-uniform LDS broadcast
        acc[c4].x = fmaf(xk, wv.x, acc[c4].x);
        acc[c4].y = fmaf(xk, wv.y, acc[c4].y);
        acc[c4].z = fmaf(xk, wv.z, acc[c4].z);
        acc[c4].w = fmaf(xk, wv.w, acc[c4].w);
      }
    }
  }

  #pragma unroll
  for (int hd = 0; hd < NH; ++hd) {
    const float4 a0 = acc[2 * hd];
    const float4 a1 = acc[2 * hd + 1];
    const float4 As0 = *(const float4*)(G.as + hd * NC);
    const float4 As1 = *(const float4*)(G.as + hd * NC + 4);
    const float4 Ad0 = *(const float4*)(G.ad + hd * NC);
    const float4 Ad1 = *(const float4*)(G.ad + hd * NC + 4);
    float ssrc = a0.x*As0.x + a0.y*As0.y + a0.z*As0.z + a0.w*As0.w
               + a1.x*As1.x + a1.y*As1.y + a1.z*As1.z + a1.w*As1.w;
    float sdst = a0.x*Ad0.x + a0.y*Ad0.y + a0.z*Ad0.z + a0.w*Ad0.w
               + a1.x*Ad1.x + a1.y*Ad1.y + a1.z*Ad1.z + a1.w*Ad1.w;
    G.as2[n * NH + hd] = f2h(ssrc);
    G.a_d[n * NH + hd] = sdst;
    uint4 hv;
    hv.x = (unsigned)f2h(a0.x) | ((unsigned)f2h(a0.y) << 16);
    hv.y = (unsigned)f2h(a0.z) | ((unsigned)f2h(a0.w) << 16);
    hv.z = (unsigned)f2h(a1.x) | ((unsigned)f2h(a1.y) << 16);
    hv.w = (unsigned)f2h(a1.z) | ((unsigned)f2h(a1.w) << 16);
    G.h2[(size_t)n * NH + hd] = hv;
  }
}

// bucket-level histogram: LDS 196 bins per 2048-edge block
__global__ __launch_bounds__(256) void k_hcnt(GT t) {
  const GP G = t.g[blockIdx.z];
  __shared__ int lh[NBUCK];
  const int tid = threadIdx.x;
  const int e0 = blockIdx.x * BCH;
  for (int i = tid; i < NBUCK; i += 256) lh[i] = 0;
  __syncthreads();
  #pragma unroll
  for (int k = 0; k < EPB; ++k) {
    const int e = e0 + k * 256 + tid;
    if (e < NE) atomicAdd(&lh[G.ei[NE + e] >> 8], 1);
  }
  __syncthreads();
  for (int i = tid; i < NBUCK; i += 256) {
    int c = lh[i];
    if (c) atomicAdd(&G.bcount[i], c);
  }
}

// scan 196 bucket counts -> bstart / bcursor
__global__ __launch_bounds__(256) void k_scanb(GT t) {
  const GP G = t.g[blockIdx.z];
  __shared__ int s[256];
  const int tid = threadIdx.x;
  int v = (tid < NBUCK) ? G.bcount[tid] : 0;
  s[tid] = v;
  __syncthreads();
  for (int off = 1; off < 256; off <<= 1) {
    int u = (tid >= off) ? s[tid - off] : 0;
    __syncthreads();
    s[tid] += u;
    __syncthreads();
  }
  if (tid < NBUCK) {
    int excl = s[tid] - v;
    G.bcursor[tid] = excl;
    G.bstart[tid] = excl;
  }
  if (tid == 0) G.bstart[NBUCK] = NE;
}

// phase 1: bin edges into 196 dense per-bucket runs of packed (dst_local<<16|src)
__global__ __launch_bounds__(256) void k_bin(GT t) {
  const GP G = t.g[blockIdx.z];
  __shared__ int lh[NBUCK];
  __shared__ int lbase[NBUCK];
  __shared__ int lcur[NBUCK];
  const int tid = threadIdx.x;
  const int e0 = blockIdx.x * BCH;
  for (int i = tid; i < NBUCK; i += 256) lh[i] = 0;
  __syncthreads();
  int dsts[EPB], srcs[EPB];
  #pragma unroll
  for (int k = 0; k < EPB; ++k) {
    const int e = e0 + k * 256 + tid;
    if (e < NE) {
      int dst = G.ei[NE + e];
      srcs[k] = G.ei[e];
      dsts[k] = dst;
      atomicAdd(&lh[dst >> 8], 1);
    } else dsts[k] = -1;
  }
  __syncthreads();
  for (int i = tid; i < NBUCK; i += 256) {
    int c = lh[i];
    lbase[i] = c ? atomicAdd(&G.bcursor[i], c) : 0;
    lcur[i] = 0;
  }
  __syncthreads();
  #pragma unroll
  for (int k = 0; k < EPB; ++k) {
    if (dsts[k] >= 0) {
      int b = dsts[k] >> 8;
      int pos = lbase[b] + atomicAdd(&lcur[b], 1);
      G.pairs[pos] = (unsigned int)srcs[k] | ((unsigned int)(dsts[k] & 255) << 16);
    }
  }
}

// phase 2: one block per bucket. LDS counting sort with key (dst_local,seg):
// emits per-(node,seg) offsets offs2[] and a csr that is dst-major, seg-sorted.
__global__ __launch_bounds__(256) void k_scat2(GT t) {
  const GP G = t.g[blockIdx.z];
  const int b = blockIdx.x;
  const int d0 = b << 8;
  __shared__ int cnt[256 * NSEG];   // 16 KB
  __shared__ int cur[256 * NSEG];   // 16 KB
  __shared__ int ssum[256];
  const int tid = threadIdx.x;
  const int estart = G.bstart[b];
  const int eend = G.bstart[b + 1];
  for (int i = tid; i < 256 * NSEG; i += 256) cnt[i] = 0;
  __syncthreads();
  for (int e = estart + tid; e < eend; e += 256) {
    unsigned p = G.pairs[e];
    int key = (int)(((p >> 16) << 4) | ((p & 0xFFFFu) >> 12));
    atomicAdd(&cnt[key], 1);
  }
  __syncthreads();
  // scan 4096 keys; thread t owns keys t*16..t*16+15 (= dst_local t, all segs)
  int local[NSEG];
  int sum = 0;
  #pragma unroll
  for (int i = 0; i < NSEG; ++i) { local[i] = sum; sum += cnt[tid * NSEG + i]; }
  ssum[tid] = sum;
  __syncthreads();
  int run = sum;
  for (int off = 1; off < 256; off <<= 1) {
    int u = (tid >= off) ? ssum[tid - off] : 0;
    __syncthreads();
    run += u;
    ssum[tid] = run;
    __syncthreads();
  }
  const int texcl = run - sum;
  int* o2 = G.offs2 + ((size_t)d0 << 4);
  #pragma unroll
  for (int i = 0; i < NSEG; ++i) {
    int v = estart + texcl + local[i];
    cur[tid * NSEG + i] = v;
    o2[tid * NSEG + i] = v;
  }
  if (b == NBUCK - 1 && tid == 0) G.offs2[(size_t)NBUCK * 256 * NSEG] = eend;
  __syncthreads();
  for (int e = estart + tid; e < eend; e += 256) {
    unsigned p = G.pairs[e];
    int key = (int)(((p >> 16) << 4) | ((p & 0xFFFFu) >> 12));
    int pos = atomicAdd(&cur[key], 1);
    G.csr[pos] = (int)(p & 0xFFFFu);
  }
}

// gather aggregation: thread (dst,head), segment-synchronized walk.
// All threads in a block process src-segment s together, then barrier ->
// the live h2 window per XCD stays ~1 segment (590 KB) -> L2-resident.
__global__ __launch_bounds__(256) void k_agg(GT t) {
  const GP G = t.g[blockIdx.z];
  const int gid = blockIdx.x * 256 + threadIdx.x;
  const bool active = (gid < NN * NH);
  int n = 0, head = 0;
  if (active) { n = gid / NH; head = gid - n * NH; }
  float denom = 0.f;
  float4 acc0 = make_float4(0.f, 0.f, 0.f, 0.f);
  float4 acc1 = make_float4(0.f, 0.f, 0.f, 0.f);
  if (active) {
    const float ad_n = G.a_d[n * NH + head];
    const float as_n = h2f(G.as2[n * NH + head]);
    float sl = as_n + ad_n;
    sl = (sl > 0.f) ? sl : NEG * sl;
    float wl = __expf(sl);
    uint4 hs = G.h2[(size_t)n * NH + head];
    denom = wl;
    acc0.x = wl * hlo(hs.x); acc0.y = wl * hhi(hs.x);
    acc0.z = wl * hlo(hs.y); acc0.w = wl * hhi(hs.y);
    acc1.x = wl * hlo(hs.z); acc1.y = wl * hhi(hs.z);
    acc1.z = wl * hlo(hs.w); acc1.w = wl * hhi(hs.w);
  }
  const float ad_n = active ? G.a_d[n * NH + head] : 0.f;
  const int* o2 = G.offs2 + ((size_t)n << 4);
  int st = active ? o2[0] : 0;
  for (int s = 0; s < 13; ++s) {
    int en = active ? o2[s + 1] : 0;
    int e = st;
    for (; e + 2 <= en; e += 2) {
      int s0 = G.csr[e];
      int s1 = G.csr[e + 1];
      float t0 = h2f(G.as2[s0 * NH + head]) + ad_n;
      float t1 = h2f(G.as2[s1 * NH + head]) + ad_n;
      uint4 v0 = G.h2[(size_t)s0 * NH + head];
      uint4 v1 = G.h2[(size_t)s1 * NH + head];
      t0 = (t0 > 0.f) ? t0 : NEG * t0;
      t1 = (t1 > 0.f) ? t1 : NEG * t1;
      float w0 = __expf(t0);
      float w1 = __expf(t1);
      denom += w0 + w1;
      acc0.x = fmaf(w0, hlo(v0.x), acc0.x); acc0.y = fmaf(w0, hhi(v0.x), acc0.y);
      acc0.z = fmaf(w0, hlo(v0.y), acc0.z); acc0.w = fmaf(w0, hhi(v0.y), acc0.w);
      acc1.x = fmaf(w0, hlo(v0.z), acc1.x); acc1.y = fmaf(w0, hhi(v0.z), acc1.y);
      acc1.z = fmaf(w0, hlo(v0.w), acc1.z); acc1.w = fmaf(w0, hhi(v0.w), acc1.w);
      acc0.x = fmaf(w1, hlo(v1.x), acc0.x); acc0.y = fmaf(w1, hhi(v1.x), acc0.y);
      acc0.z = fmaf(w1, hlo(v1.y), acc0.z); acc0.w = fmaf(w1, hhi(v1.y), acc0.w);
      acc1.x = fmaf(w1, hlo(v1.z), acc1.x); acc1.y = fmaf(w1, hhi(v1.z), acc1.y);
      acc1.z = fmaf(w1, hlo(v1.w), acc1.z); acc1.w = fmaf(w1, hhi(v1.w), acc1.w);
    }
    if (e < en) {
      int src = G.csr[e];
      float sc = h2f(G.as2[src * NH + head]) + ad_n;
      sc = (sc > 0.f) ? sc : NEG * sc;
      float w = __expf(sc);
      uint4 hv = G.h2[(size_t)src * NH + head];
      denom += w;
      acc0.x = fmaf(w, hlo(hv.x), acc0.x); acc0.y = fmaf(w, hhi(hv.x), acc0.y);
      acc0.z = fmaf(w, hlo(hv.y), acc0.z); acc0.w = fmaf(w, hhi(hv.y), acc0.w);
      acc1.x = fmaf(w, hlo(hv.z), acc1.x); acc1.y = fmaf(w, hhi(hv.z), acc1.y);
      acc1.z = fmaf(w, hlo(hv.w), acc1.z); acc1.w = fmaf(w, hhi(hv.w), acc1.w);
    }
    st = en;
    __syncthreads();
  }
  if (!active) return;
  float inv = 1.f / (denom + 1e-16f);
  const float* bp = G.b + head * NC;
  float4 o0, o1;
  o0.x = acc0.x * inv + bp[0]; o0.y = acc0.y * inv + bp[1];
  o0.z = acc0.z * inv + bp[2]; o0.w = acc0.w * inv + bp[3];
  o1.x = acc1.x * inv + bp[4]; o1.y = acc1.y * inv + bp[5];
  o1.z = acc1.z * inv + bp[6]; o1.w = acc1.w * inv + bp[7];
  float4* op = (float4*)(G.out + (size_t)n * HCH + head * NC);
  op[0] = o0; op[1] = o1;
}

// relu(concat) @ fnn_W + fnn_b -> softmax(2). One wave per node.
__global__ __launch_bounds__(256) void k_fnn(const float* __restrict__ o1,
                                             const float* __restrict__ o2,
                                             const float* __restrict__ o3,
                                             const float* __restrict__ fw,
                                             const float* __restrict__ fb,
                                             float* __restrict__ out) {
  const int tid = blockIdx.x * 256 + threadIdx.x;
  const int n = tid >> 6;
  const int lane = tid & 63;
  if (n >= NN) return;
  float acc0 = 0.f, acc1 = 0.f;
  for (int j = lane; j < 3 * HCH; j += 64) {
    const int g = j / HCH;
    const int c = j - g * HCH;
    const float* og = (g == 0) ? o1 : (g == 1) ? o2 : o3;
    float v = og[(size_t)n * HCH + c];
    v = v > 0.f ? v : 0.f;
    acc0 = fmaf(v, fw[2 * j], acc0);
    acc1 = fmaf(v, fw[2 * j + 1], acc1);
  }
  #pragma unroll
  for (int off = 32; off > 0; off >>= 1) {
    acc0 += __shfl_down(acc0, off, 64);
    acc1 += __shfl_down(acc1, off, 64);
  }
  if (lane == 0) {
    float l0 = acc0 + fb[0], l1 = acc1 + fb[1];
    float m = fmaxf(l0, l1);
    float e0 = __expf(l0 - m), e1 = __expf(l1 - m);
    float inv = 1.f / (e0 + e1);
    out[(size_t)n * 2] = e0 * inv;
    out[(size_t)n * 2 + 1] = e1 * inv;
  }
}

extern "C" void kernel_launch(void* const* d_in, const int* in_sizes, int n_in,
                              void* d_out, int out_size, void* d_ws, size_t ws_size,
                              hipStream_t stream) {
  (void)in_sizes; (void)n_in; (void)out_size; (void)ws_size;
  GT t;
  char* w = (char*)d_ws;
  size_t off = 0;
  auto carve = [&](size_t bytes) -> void* {
    void* p = w + off;
    off = (off + bytes + 255) & ~(size_t)255;
    return p;
  };
  for (int g = 0; g < 3; ++g) {
    GP& G = t.g[g];
    G.x  = (const float*)d_in[6 * g + 0];
    G.ei = (const int*)d_in[6 * g + 1];     // harness stores int64 inputs as int32
    G.W  = (const float*)d_in[6 * g + 2];
    G.as = (const float*)d_in[6 * g + 3];
    G.ad = (const float*)d_in[6 * g + 4];
    G.b  = (const float*)d_in[6 * g + 5];
    G.h2   = (uint4*)carve((size_t)NN * NH * 16);
    G.as2  = (unsigned short*)carve((size_t)NN * NH * 2);
    G.a_d  = (float*)carve((size_t)NN * NH * 4);
    G.out  = (float*)carve((size_t)NN * HCH * 4);
    G.offs2 = (int*)carve(((size_t)NBUCK * 256 * NSEG + 1) * 4);
    G.bcount  = (int*)carve((size_t)NBUCK * 4);
    G.bcursor = (int*)carve((size_t)NBUCK * 4);
    G.bstart  = (int*)carve((size_t)(NBUCK + 1) * 4);
    G.pairs = (unsigned int*)carve((size_t)NE * 4);
    G.csr  = (int*)carve((size_t)NE * 4);
  }
  const float* fw = (const float*)d_in[18];
  const float* fb = (const float*)d_in[19];
  float* outp = (float*)d_out;

  dim3 b256(256, 1, 1);
  k_gemm   <<<dim3((NN + 255) / 256, 1, 3), b256, 0, stream>>>(t);
  k_hcnt   <<<dim3((NE + BCH - 1) / BCH, 1, 3), b256, 0, stream>>>(t);
  k_scanb  <<<dim3(1, 1, 3), b256, 0, stream>>>(t);
  k_bin    <<<dim3((NE + BCH - 1) / BCH, 1, 3), b256, 0, stream>>>(t);
  k_scat2  <<<dim3(NBUCK, 1, 3), b256, 0, stream>>>(t);
  k_agg    <<<dim3((NN * NH + 255) / 256, 1, 3), b256, 0, stream>>>(t);
  k_fnn    <<<(NN * 64 + 255) / 256, b256, 0, stream>>>(t.g[0].out, t.g[1].out, t.g[2].out, fw, fb, outp);
}

// Round 10
// 497.880 us; speedup vs baseline: 2.6241x; 1.0631x over previous
//
#include <hip/hip_runtime.h>
#include <hip/hip_fp16.h>

#define NN 50000
#define NE 1600000
#define DD 128
#define NH 9
#define NC 8
#define HCH 72
#define NEG 0.2f
#define NBUCK 196      // ceil(50000/256), 256 dst nodes per bucket
#define NSEG 16        // src segments of 4096 nodes (only 0..12 non-empty)
#define SPAD 17        // padded seg stride in k_scat2 LDS (bank-conflict fix)
#define EPB 8          // edges per thread in k_bin/k_hcnt
#define BCH (256*EPB)  // 2048 edges per block

__device__ __forceinline__ unsigned short f2h(float f) {
  return __half_as_ushort(__float2half_rn(f));
}
__device__ __forceinline__ float h2f(unsigned short u) {
  return __half2float(__ushort_as_half(u));
}
__device__ __forceinline__ float hlo(unsigned u) {
  return __half2float(__ushort_as_half((unsigned short)(u & 0xFFFFu)));
}
__device__ __forceinline__ float hhi(unsigned u) {
  return __half2float(__ushort_as_half((unsigned short)(u >> 16)));
}

struct GP {
  const float* x; const int* ei; const float* W;
  const float* as; const float* ad; const float* b;
  uint4* h2;                // [NN*9] uint4: 8 fp16 channels per (node,head)
  unsigned short* as2;      // [NN*9] fp16 src-attention scores
  float* a_d; float* out;
  int* offs2;               // [NBUCK*256*16+1] per-(node,seg) csr offsets
  int* bcount;              // [NBUCK]
  int* bcursor;             // [NBUCK]
  int* bstart;              // [NBUCK+1]
  unsigned int* pairs; int* csr;
};
struct GT { GP g[3]; };

// h = x@W: one thread per NODE, all 72 channels in registers.
// W staged in LDS (wave-uniform broadcast reads). Block 0 zeroes bcount.
__global__ __launch_bounds__(256) void k_gemm(GT t) {
  const GP G = t.g[blockIdx.z];
  __shared__ float Wl[DD * HCH];   // 36 KB
  const int tid = threadIdx.x;
  if (blockIdx.x == 0 && tid < NBUCK) G.bcount[tid] = 0;
  {
    const float4* Wg = (const float4*)G.W;
    float4* Wd = (float4*)Wl;
    #pragma unroll
    for (int i = 0; i < 9; ++i) Wd[tid + 256 * i] = Wg[tid + 256 * i];  // 2304 = 256*9
  }
  const int n = blockIdx.x * 256 + tid;
  __syncthreads();
  if (n >= NN) return;

  float4 acc[18];
  #pragma unroll
  for (int i = 0; i < 18; ++i) acc[i] = make_float4(0.f, 0.f, 0.f, 0.f);
  const float4* x4 = (const float4*)(G.x + (size_t)n * DD);

  for (int k4 = 0; k4 < DD / 4; ++k4) {
    const float4 xv = x4[k4];
    const float* w0 = &Wl[(k4 * 4) * HCH];
    #pragma unroll
    for (int kk = 0; kk < 4; ++kk) {
      const float xk = (kk == 0) ? xv.x : (kk == 1) ? xv.y : (kk == 2) ? xv.z : xv.w;
      const float4* wr = (const float4*)(w0 + kk * HCH);
      #pragma unroll
      for (int c4 = 0; c4 < 18; ++c4) {
        float4 wv = wr[c4];                       // wave-uniform LDS broadcast
        acc[c4].x = fmaf(xk, wv.x, acc[c4].x);
        acc[c4].y = fmaf(xk, wv.y, acc[c4].y);
        acc[c4].z = fmaf(xk, wv.z, acc[c4].z);
        acc[c4].w = fmaf(xk, wv.w, acc[c4].w);
      }
    }
  }

  #pragma unroll
  for (int hd = 0; hd < NH; ++hd) {
    const float4 a0 = acc[2 * hd];
    const float4 a1 = acc[2 * hd + 1];
    const float4 As0 = *(const float4*)(G.as + hd * NC);
    const float4 As1 = *(const float4*)(G.as + hd * NC + 4);
    const float4 Ad0 = *(const float4*)(G.ad + hd * NC);
    const float4 Ad1 = *(const float4*)(G.ad + hd * NC + 4);
    float ssrc = a0.x*As0.x + a0.y*As0.y + a0.z*As0.z + a0.w*As0.w
               + a1.x*As1.x + a1.y*As1.y + a1.z*As1.z + a1.w*As1.w;
    float sdst = a0.x*Ad0.x + a0.y*Ad0.y + a0.z*Ad0.z + a0.w*Ad0.w
               + a1.x*Ad1.x + a1.y*Ad1.y + a1.z*Ad1.z + a1.w*Ad1.w;
    G.as2[n * NH + hd] = f2h(ssrc);
    G.a_d[n * NH + hd] = sdst;
    uint4 hv;
    hv.x = (unsigned)f2h(a0.x) | ((unsigned)f2h(a0.y) << 16);
    hv.y = (unsigned)f2h(a0.z) | ((unsigned)f2h(a0.w) << 16);
    hv.z = (unsigned)f2h(a1.x) | ((unsigned)f2h(a1.y) << 16);
    hv.w = (unsigned)f2h(a1.z) | ((unsigned)f2h(a1.w) << 16);
    G.h2[(size_t)n * NH + hd] = hv;
  }
}

// bucket-level histogram: LDS 196 bins per 2048-edge block
__global__ __launch_bounds__(256) void k_hcnt(GT t) {
  const GP G = t.g[blockIdx.z];
  __shared__ int lh[NBUCK];
  const int tid = threadIdx.x;
  const int e0 = blockIdx.x * BCH;
  for (int i = tid; i < NBUCK; i += 256) lh[i] = 0;
  __syncthreads();
  #pragma unroll
  for (int k = 0; k < EPB; ++k) {
    const int e = e0 + k * 256 + tid;
    if (e < NE) atomicAdd(&lh[G.ei[NE + e] >> 8], 1);
  }
  __syncthreads();
  for (int i = tid; i < NBUCK; i += 256) {
    int c = lh[i];
    if (c) atomicAdd(&G.bcount[i], c);
  }
}

// scan 196 bucket counts -> bstart / bcursor
__global__ __launch_bounds__(256) void k_scanb(GT t) {
  const GP G = t.g[blockIdx.z];
  __shared__ int s[256];
  const int tid = threadIdx.x;
  int v = (tid < NBUCK) ? G.bcount[tid] : 0;
  s[tid] = v;
  __syncthreads();
  for (int off = 1; off < 256; off <<= 1) {
    int u = (tid >= off) ? s[tid - off] : 0;
    __syncthreads();
    s[tid] += u;
    __syncthreads();
  }
  if (tid < NBUCK) {
    int excl = s[tid] - v;
    G.bcursor[tid] = excl;
    G.bstart[tid] = excl;
  }
  if (tid == 0) G.bstart[NBUCK] = NE;
}

// phase 1: bin edges into 196 dense per-bucket runs of packed (dst_local<<16|src)
__global__ __launch_bounds__(256) void k_bin(GT t) {
  const GP G = t.g[blockIdx.z];
  __shared__ int lh[NBUCK];
  __shared__ int lbase[NBUCK];
  __shared__ int lcur[NBUCK];
  const int tid = threadIdx.x;
  const int e0 = blockIdx.x * BCH;
  for (int i = tid; i < NBUCK; i += 256) lh[i] = 0;
  __syncthreads();
  int dsts[EPB], srcs[EPB];
  #pragma unroll
  for (int k = 0; k < EPB; ++k) {
    const int e = e0 + k * 256 + tid;
    if (e < NE) {
      int dst = G.ei[NE + e];
      srcs[k] = G.ei[e];
      dsts[k] = dst;
      atomicAdd(&lh[dst >> 8], 1);
    } else dsts[k] = -1;
  }
  __syncthreads();
  for (int i = tid; i < NBUCK; i += 256) {
    int c = lh[i];
    lbase[i] = c ? atomicAdd(&G.bcursor[i], c) : 0;
    lcur[i] = 0;
  }
  __syncthreads();
  #pragma unroll
  for (int k = 0; k < EPB; ++k) {
    if (dsts[k] >= 0) {
      int b = dsts[k] >> 8;
      int pos = lbase[b] + atomicAdd(&lcur[b], 1);
      G.pairs[pos] = (unsigned int)srcs[k] | ((unsigned int)(dsts[k] & 255) << 16);
    }
  }
}

// phase 2: one block per bucket. LDS counting sort with key (dst_local,seg):
// emits per-(node,seg) offsets offs2[] and a csr that is dst-major, seg-sorted.
// LDS uses stride 17 to avoid the 2-bank aliasing of stride 16.
__global__ __launch_bounds__(256) void k_scat2(GT t) {
  const GP G = t.g[blockIdx.z];
  const int b = blockIdx.x;
  const int d0 = b << 8;
  __shared__ int cnt[256 * SPAD];   // 17.4 KB
  __shared__ int cur[256 * SPAD];   // 17.4 KB
  __shared__ int ssum[256];
  const int tid = threadIdx.x;
  const int estart = G.bstart[b];
  const int eend = G.bstart[b + 1];
  for (int i = tid; i < 256 * SPAD; i += 256) cnt[i] = 0;
  __syncthreads();
  for (int e = estart + tid; e < eend; e += 256) {
    unsigned p = G.pairs[e];
    int key = (int)((p >> 16) * SPAD + ((p & 0xFFFFu) >> 12));
    atomicAdd(&cnt[key], 1);
  }
  __syncthreads();
  // scan: thread t owns keys t*SPAD .. t*SPAD+15 (= dst_local t, all segs)
  int local[NSEG];
  int sum = 0;
  #pragma unroll
  for (int i = 0; i < NSEG; ++i) { local[i] = sum; sum += cnt[tid * SPAD + i]; }
  ssum[tid] = sum;
  __syncthreads();
  int run = sum;
  for (int off = 1; off < 256; off <<= 1) {
    int u = (tid >= off) ? ssum[tid - off] : 0;
    __syncthreads();
    run += u;
    ssum[tid] = run;
    __syncthreads();
  }
  const int texcl = run - sum;
  int* o2 = G.offs2 + ((size_t)d0 << 4);
  #pragma unroll
  for (int i = 0; i < NSEG; ++i) {
    int v = estart + texcl + local[i];
    cur[tid * SPAD + i] = v;
    o2[tid * NSEG + i] = v;
  }
  if (b == NBUCK - 1 && tid == 0) G.offs2[(size_t)NBUCK * 256 * NSEG] = eend;
  __syncthreads();
  for (int e = estart + tid; e < eend; e += 256) {
    unsigned p = G.pairs[e];
    int key = (int)((p >> 16) * SPAD + ((p & 0xFFFFu) >> 12));
    int pos = atomicAdd(&cur[key], 1);
    G.csr[pos] = (int)(p & 0xFFFFu);
  }
}

// gather aggregation: thread (dst,head). Segment-GROUP synchronized walk:
// barrier every 4 src-segments (working set ~2.4MB < 4MiB XCD L2), with
// 4-edge batched loads for memory-level parallelism.
__global__ __launch_bounds__(256) void k_agg(GT t) {
  const GP G = t.g[blockIdx.z];
  const int gid = blockIdx.x * 256 + threadIdx.x;
  const bool active = (gid < NN * NH);
  int n = 0, head = 0;
  if (active) { n = gid / NH; head = gid - n * NH; }
  float denom = 0.f;
  float4 acc0 = make_float4(0.f, 0.f, 0.f, 0.f);
  float4 acc1 = make_float4(0.f, 0.f, 0.f, 0.f);
  float ad_n = 0.f;
  int gb[5] = {0, 0, 0, 0, 0};
  if (active) {
    ad_n = G.a_d[n * NH + head];
    const int* o2 = G.offs2 + ((size_t)n << 4);
    gb[0] = o2[0]; gb[1] = o2[4]; gb[2] = o2[8]; gb[3] = o2[12]; gb[4] = o2[13];
    float sl = h2f(G.as2[n * NH + head]) + ad_n;
    sl = (sl > 0.f) ? sl : NEG * sl;
    float wl = __expf(sl);
    uint4 hs = G.h2[(size_t)n * NH + head];
    denom = wl;
    acc0.x = wl * hlo(hs.x); acc0.y = wl * hhi(hs.x);
    acc0.z = wl * hlo(hs.y); acc0.w = wl * hhi(hs.y);
    acc1.x = wl * hlo(hs.z); acc1.y = wl * hhi(hs.z);
    acc1.z = wl * hlo(hs.w); acc1.w = wl * hhi(hs.w);
  }
  #pragma unroll
  for (int g = 0; g < 4; ++g) {
    int e = gb[g];
    const int en = gb[g + 1];
    for (; e + 4 <= en; e += 4) {
      // batch loads: 4 ids -> 4 scores + 4 rows all in flight
      int s0 = G.csr[e];
      int s1 = G.csr[e + 1];
      int s2 = G.csr[e + 2];
      int s3 = G.csr[e + 3];
      unsigned short u0 = G.as2[s0 * NH + head];
      unsigned short u1 = G.as2[s1 * NH + head];
      unsigned short u2 = G.as2[s2 * NH + head];
      unsigned short u3 = G.as2[s3 * NH + head];
      uint4 v0 = G.h2[(size_t)s0 * NH + head];
      uint4 v1 = G.h2[(size_t)s1 * NH + head];
      uint4 v2 = G.h2[(size_t)s2 * NH + head];
      uint4 v3 = G.h2[(size_t)s3 * NH + head];
      float t0 = h2f(u0) + ad_n;
      float t1 = h2f(u1) + ad_n;
      float t2 = h2f(u2) + ad_n;
      float t3 = h2f(u3) + ad_n;
      t0 = (t0 > 0.f) ? t0 : NEG * t0;
      t1 = (t1 > 0.f) ? t1 : NEG * t1;
      t2 = (t2 > 0.f) ? t2 : NEG * t2;
      t3 = (t3 > 0.f) ? t3 : NEG * t3;
      float w0 = __expf(t0);
      float w1 = __expf(t1);
      float w2 = __expf(t2);
      float w3 = __expf(t3);
      denom += (w0 + w1) + (w2 + w3);
      acc0.x = fmaf(w0, hlo(v0.x), acc0.x); acc0.y = fmaf(w0, hhi(v0.x), acc0.y);
      acc0.z = fmaf(w0, hlo(v0.y), acc0.z); acc0.w = fmaf(w0, hhi(v0.y), acc0.w);
      acc1.x = fmaf(w0, hlo(v0.z), acc1.x); acc1.y = fmaf(w0, hhi(v0.z), acc1.y);
      acc1.z = fmaf(w0, hlo(v0.w), acc1.z); acc1.w = fmaf(w0, hhi(v0.w), acc1.w);
      acc0.x = fmaf(w1, hlo(v1.x), acc0.x); acc0.y = fmaf(w1, hhi(v1.x), acc0.y);
      acc0.z = fmaf(w1, hlo(v1.y), acc0.z); acc0.w = fmaf(w1, hhi(v1.y), acc0.w);
      acc1.x = fmaf(w1, hlo(v1.z), acc1.x); acc1.y = fmaf(w1, hhi(v1.z), acc1.y);
      acc1.z = fmaf(w1, hlo(v1.w), acc1.z); acc1.w = fmaf(w1, hhi(v1.w), acc1.w);
      acc0.x = fmaf(w2, hlo(v2.x), acc0.x); acc0.y = fmaf(w2, hhi(v2.x), acc0.y);
      acc0.z = fmaf(w2, hlo(v2.y), acc0.z); acc0.w = fmaf(w2, hhi(v2.y), acc0.w);
      acc1.x = fmaf(w2, hlo(v2.z), acc1.x); acc1.y = fmaf(w2, hhi(v2.z), acc1.y);
      acc1.z = fmaf(w2, hlo(v2.w), acc1.z); acc1.w = fmaf(w2, hhi(v2.w), acc1.w);
      acc0.x = fmaf(w3, hlo(v3.x), acc0.x); acc0.y = fmaf(w3, hhi(v3.x), acc0.y);
      acc0.z = fmaf(w3, hlo(v3.y), acc0.z); acc0.w = fmaf(w3, hhi(v3.y), acc0.w);
      acc1.x = fmaf(w3, hlo(v3.z), acc1.x); acc1.y = fmaf(w3, hhi(v3.z), acc1.y);
      acc1.z = fmaf(w3, hlo(v3.w), acc1.z); acc1.w = fmaf(w3, hhi(v3.w), acc1.w);
    }
    for (; e < en; ++e) {
      int src = G.csr[e];
      float sc = h2f(G.as2[src * NH + head]) + ad_n;
      sc = (sc > 0.f) ? sc : NEG * sc;
      float w = __expf(sc);
      uint4 hv = G.h2[(size_t)src * NH + head];
      denom += w;
      acc0.x = fmaf(w, hlo(hv.x), acc0.x); acc0.y = fmaf(w, hhi(hv.x), acc0.y);
      acc0.z = fmaf(w, hlo(hv.y), acc0.z); acc0.w = fmaf(w, hhi(hv.y), acc0.w);
      acc1.x = fmaf(w, hlo(hv.z), acc1.x); acc1.y = fmaf(w, hhi(hv.z), acc1.y);
      acc1.z = fmaf(w, hlo(hv.w), acc1.z); acc1.w = fmaf(w, hhi(hv.w), acc1.w);
    }
    __syncthreads();
  }
  if (!active) return;
  float inv = 1.f / (denom + 1e-16f);
  const float* bp = G.b + head * NC;
  float4 o0, o1;
  o0.x = acc0.x * inv + bp[0]; o0.y = acc0.y * inv + bp[1];
  o0.z = acc0.z * inv + bp[2]; o0.w = acc0.w * inv + bp[3];
  o1.x = acc1.x * inv + bp[4]; o1.y = acc1.y * inv + bp[5];
  o1.z = acc1.z * inv + bp[6]; o1.w = acc1.w * inv + bp[7];
  float4* op = (float4*)(G.out + (size_t)n * HCH + head * NC);
  op[0] = o0; op[1] = o1;
}

// relu(concat) @ fnn_W + fnn_b -> softmax(2). One wave per node.
__global__ __launch_bounds__(256) void k_fnn(const float* __restrict__ o1,
                                             const float* __restrict__ o2,
                                             const float* __restrict__ o3,
                                             const float* __restrict__ fw,
                                             const float* __restrict__ fb,
                                             float* __restrict__ out) {
  const int tid = blockIdx.x * 256 + threadIdx.x;
  const int n = tid >> 6;
  const int lane = tid & 63;
  if (n >= NN) return;
  float acc0 = 0.f, acc1 = 0.f;
  for (int j = lane; j < 3 * HCH; j += 64) {
    const int g = j / HCH;
    const int c = j - g * HCH;
    const float* og = (g == 0) ? o1 : (g == 1) ? o2 : o3;
    float v = og[(size_t)n * HCH + c];
    v = v > 0.f ? v : 0.f;
    acc0 = fmaf(v, fw[2 * j], acc0);
    acc1 = fmaf(v, fw[2 * j + 1], acc1);
  }
  #pragma unroll
  for (int off = 32; off > 0; off >>= 1) {
    acc0 += __shfl_down(acc0, off, 64);
    acc1 += __shfl_down(acc1, off, 64);
  }
  if (lane == 0) {
    float l0 = acc0 + fb[0], l1 = acc1 + fb[1];
    float m = fmaxf(l0, l1);
    float e0 = __expf(l0 - m), e1 = __expf(l1 - m);
    float inv = 1.f / (e0 + e1);
    out[(size_t)n * 2] = e0 * inv;
    out[(size_t)n * 2 + 1] = e1 * inv;
  }
}

extern "C" void kernel_launch(void* const* d_in, const int* in_sizes, int n_in,
                              void* d_out, int out_size, void* d_ws, size_t ws_size,
                              hipStream_t stream) {
  (void)in_sizes; (void)n_in; (void)out_size; (void)ws_size;
  GT t;
  char* w = (char*)d_ws;
  size_t off = 0;
  auto carve = [&](size_t bytes) -> void* {
    void* p = w + off;
    off = (off + bytes + 255) & ~(size_t)255;
    return p;
  };
  for (int g = 0; g < 3; ++g) {
    GP& G = t.g[g];
    G.x  = (const float*)d_in[6 * g + 0];
    G.ei = (const int*)d_in[6 * g + 1];     // harness stores int64 inputs as int32
    G.W  = (const float*)d_in[6 * g + 2];
    G.as = (const float*)d_in[6 * g + 3];
    G.ad = (const float*)d_in[6 * g + 4];
    G.b  = (const float*)d_in[6 * g + 5];
    G.h2   = (uint4*)carve((size_t)NN * NH * 16);
    G.as2  = (unsigned short*)carve((size_t)NN * NH * 2);
    G.a_d  = (float*)carve((size_t)NN * NH * 4);
    G.out  = (float*)carve((size_t)NN * HCH * 4);
    G.offs2 = (int*)carve(((size_t)NBUCK * 256 * NSEG + 1) * 4);
    G.bcount  = (int*)carve((size_t)NBUCK * 4);
    G.bcursor = (int*)carve((size_t)NBUCK * 4);
    G.bstart  = (int*)carve((size_t)(NBUCK + 1) * 4);
    G.pairs = (unsigned int*)carve((size_t)NE * 4);
    G.csr  = (int*)carve((size_t)NE * 4);
  }
  const float* fw = (const float*)d_in[18];
  const float* fb = (const float*)d_in[19];
  float* outp = (float*)d_out;

  dim3 b256(256, 1, 1);
  k_gemm   <<<dim3((NN + 255) / 256, 1, 3), b256, 0, stream>>>(t);
  k_hcnt   <<<dim3((NE + BCH - 1) / BCH, 1, 3), b256, 0, stream>>>(t);
  k_scanb  <<<dim3(1, 1, 3), b256, 0, stream>>>(t);
  k_bin    <<<dim3((NE + BCH - 1) / BCH, 1, 3), b256, 0, stream>>>(t);
  k_scat2  <<<dim3(NBUCK, 1, 3), b256, 0, stream>>>(t);
  k_agg    <<<dim3((NN * NH + 255) / 256, 1, 3), b256, 0, stream>>>(t);
  k_fnn    <<<(NN * 64 + 255) / 256, b256, 0, stream>>>(t.g[0].out, t.g[1].out, t.g[2].out, fw, fb, outp);
}